// Round 1
// baseline (3423.940 us; speedup 1.0000x reference)
//
#include <hip/hip_runtime.h>
#include <hip/hip_bf16.h>
#include <math.h>

#define NHEADS 12
#define NTOK   50
#define NWIN   2048
#define IMGS   32
#define WPI    64
#define CDIM   384
#define QKVD   1152
#define DHID   768
#define MLPH   3072
#define SCALE_F 0.17677669529663687f

typedef short short8 __attribute__((ext_vector_type(8)));
typedef float f32x4  __attribute__((ext_vector_type(4)));
typedef __hip_bfloat16 bf16;

__device__ __forceinline__ float gelu_f(float x){
  return 0.5f*x*(1.0f+erff(x*0.7071067811865476f));
}

// ---------------- weight fp32 -> bf16 ----------------
__global__ void cvt_bf16_kernel(const float* __restrict__ x, bf16* __restrict__ y, int n){
  for (int i = blockIdx.x*blockDim.x + threadIdx.x; i < n; i += gridDim.x*blockDim.x)
    y[i] = __float2bfloat16(x[i]);
}

// ---------------- LayerNorm (optionally fused GELU), fp32 in -> bf16 out ----------------
template<bool GELU>
__global__ __launch_bounds__(256) void ln_kernel(const float* __restrict__ x, long ldx,
    const float* __restrict__ g, const float* __restrict__ b,
    bf16* __restrict__ y, int rows)
{
  int row = blockIdx.x*4 + (threadIdx.x>>6);
  if (row >= rows) return;
  int l = threadIdx.x & 63;
  const float* xr = x + (size_t)row*ldx;
  float v[6]; float s = 0.f;
  #pragma unroll
  for (int j=0;j<6;j++){ v[j] = xr[l + 64*j]; s += v[j]; }
  #pragma unroll
  for (int off=32; off; off>>=1) s += __shfl_xor(s, off, 64);
  float mean = s * (1.0f/384.0f);
  float vs = 0.f;
  #pragma unroll
  for (int j=0;j<6;j++){ float d = v[j]-mean; vs += d*d; }
  #pragma unroll
  for (int off=32; off; off>>=1) vs += __shfl_xor(vs, off, 64);
  float rstd = rsqrtf(vs*(1.0f/384.0f) + 1e-5f);
  bf16* yr = y + (size_t)row*384;
  #pragma unroll
  for (int j=0;j<6;j++){
    float o = (v[j]-mean)*rstd*g[l+64*j] + b[l+64*j];
    if (GELU) o = gelu_f(o);
    yr[l + 64*j] = __float2bfloat16(o);
  }
}

// ---------------- GEMM: C[M,N] = A[M,K](bf16) * W[N,K]^T(bf16), fp32 acc ----------------
// 128x128 tile, 4 waves, 16x16x32 MFMA. M%128==0, N%128==0, K%32==0 required.
template<bool OUT_BF16, bool BIAS, bool RES, bool GELU>
__global__ __launch_bounds__(256) void gemm_bt(
    const bf16* __restrict__ A, const bf16* __restrict__ B, void* __restrict__ Cv,
    const float* __restrict__ bias, const float* __restrict__ res,
    int M, int N, int K, int ldc, int ldres)
{
  __shared__ short As[128*32];
  __shared__ short Bs[128*32];
  const int t  = threadIdx.x;
  const int l  = t & 63;
  const int w  = t >> 6;
  const int wr = w >> 1, wc = w & 1;
  const int lr = l & 15, kg = l >> 4;
  const int bm = blockIdx.y * 128, bn = blockIdx.x * 128;
  const short* Ag = (const short*)A;
  const short* Bg = (const short*)B;
  f32x4 acc[4][4] = {};

  for (int k0 = 0; k0 < K; k0 += 32) {
    #pragma unroll
    for (int p = 0; p < 2; p++) {
      int e   = (p*256 + t) * 8;
      int row = e >> 5, col = e & 31;
      *(short8*)(&As[e]) = *(const short8*)(&Ag[(size_t)(bm+row)*K + k0 + col]);
      *(short8*)(&Bs[e]) = *(const short8*)(&Bg[(size_t)(bn+row)*K + k0 + col]);
    }
    __syncthreads();
    short8 af[4], bfm[4];
    #pragma unroll
    for (int m=0;m<4;m++) af[m]  = *(const short8*)(&As[(wr*64 + m*16 + lr)*32 + kg*8]);
    #pragma unroll
    for (int n=0;n<4;n++) bfm[n] = *(const short8*)(&Bs[(wc*64 + n*16 + lr)*32 + kg*8]);
    #pragma unroll
    for (int m=0;m<4;m++)
      #pragma unroll
      for (int n=0;n<4;n++)
        acc[m][n] = __builtin_amdgcn_mfma_f32_16x16x32_bf16(af[m], bfm[n], acc[m][n], 0,0,0);
    __syncthreads();
  }

  #pragma unroll
  for (int m=0;m<4;m++){
    int row0 = bm + wr*64 + m*16 + kg*4;
    #pragma unroll
    for (int n=0;n<4;n++){
      int col = bn + wc*64 + n*16 + lr;
      float bv = BIAS ? bias[col] : 0.0f;
      #pragma unroll
      for (int r=0;r<4;r++){
        float val = acc[m][n][r] + bv;
        if (RES)  val += res[(size_t)(row0+r)*ldres + col];
        if (GELU) val = gelu_f(val);
        if (OUT_BF16) ((bf16*)Cv)[(size_t)(row0+r)*ldc + col] = __float2bfloat16(val);
        else          ((float*)Cv)[(size_t)(row0+r)*ldc + col] = val;
      }
    }
  }
}

// ---------------- cls attention: 32 images x 64 window-tokens, 12 heads, d=32 ----------------
__global__ __launch_bounds__(256) void attn_cls_kernel(const float* __restrict__ qkv,
                                                       bf16* __restrict__ y)
{
  int img = blockIdx.x, h = blockIdx.y;
  __shared__ float q[64][33], k[64][33], v[64][33];
  __shared__ float s[64][65];
  int t = threadIdx.x;
  for (int idx=t; idx<64*32; idx+=256){
    int i = idx>>5, d = idx&31;
    const float* base = qkv + ((size_t)(img*64+i))*QKVD + h*32 + d;
    q[i][d] = base[0]; k[i][d] = base[384]; v[i][d] = base[768];
  }
  __syncthreads();
  for (int idx=t; idx<64*64; idx+=256){
    int i = idx>>6, j = idx&63;
    float a = 0.f;
    #pragma unroll
    for (int d=0; d<32; d++) a += q[i][d]*k[j][d];
    s[i][j] = a * SCALE_F;
  }
  __syncthreads();
  if (t < 64){
    float m = -1e30f;
    for (int j=0;j<64;j++) m = fmaxf(m, s[t][j]);
    float sum = 0.f;
    for (int j=0;j<64;j++){ float e = __expf(s[t][j]-m); s[t][j]=e; sum+=e; }
    float inv = 1.0f/sum;
    for (int j=0;j<64;j++) s[t][j] *= inv;
  }
  __syncthreads();
  for (int idx=t; idx<64*32; idx+=256){
    int i = idx>>5, d = idx&31;
    float a = 0.f;
    for (int j=0;j<64;j++) a += s[i][j]*v[j][d];
    y[((size_t)(img*64+i))*CDIM + h*32 + d] = __float2bfloat16(a);
  }
}

// ---------------- window attention: 50 tokens, rel-pos bias on [1:,1:], + mask ----------------
__global__ __launch_bounds__(256) void attn_win_kernel(const float* __restrict__ qkv,
    const float* __restrict__ mask, const float* __restrict__ rel_pos,
    bf16* __restrict__ y, int win0)
{
  int lw = blockIdx.x, h = blockIdx.y;
  int wgl = win0 + lw;
  __shared__ float q[50][33], k[50][33], v[50][33];
  __shared__ float s[50][51];
  __shared__ float rp[169];
  int t = threadIdx.x;
  for (int idx=t; idx<50*32; idx+=256){
    int i = idx>>5, d = idx&31;
    const float* base = qkv + ((size_t)(lw*50+i))*QKVD + h*32 + d;
    q[i][d] = base[0]; k[i][d] = base[384]; v[i][d] = base[768];
  }
  for (int idx=t; idx<169; idx+=256) rp[idx] = rel_pos[idx*NHEADS + h];
  __syncthreads();
  const float* mrow = mask + (size_t)wgl*2500;
  for (int idx=t; idx<2500; idx+=256){
    int i = idx/50, j = idx - i*50;
    float a = 0.f;
    #pragma unroll
    for (int d=0; d<32; d++) a += q[i][d]*k[j][d];
    a *= SCALE_F;
    if (i > 0 && j > 0){
      int qi = i-1, kj = j-1;
      int ridx = ((qi/7)-(kj/7)+6)*13 + ((qi%7)-(kj%7)+6);
      a += rp[ridx];
    }
    a += mrow[idx];
    s[i][j] = a;
  }
  __syncthreads();
  if (t < 50){
    float m = -1e30f;
    for (int j=0;j<50;j++) m = fmaxf(m, s[t][j]);
    float sum = 0.f;
    for (int j=0;j<50;j++){ float e = __expf(s[t][j]-m); s[t][j]=e; sum+=e; }
    float inv = 1.0f/sum;
    for (int j=0;j<50;j++) s[t][j] *= inv;
  }
  __syncthreads();
  for (int idx=t; idx<50*32; idx+=256){
    int i = idx>>5, d = idx&31;
    float a = 0.f;
    for (int j=0;j<50;j++) a += s[i][j]*v[j][d];
    y[((size_t)(lw*50+i))*CDIM + h*32 + d] = __float2bfloat16(a);
  }
}

// ---------------------------------------------------------------------------
extern "C" void kernel_launch(void* const* d_in, const int* in_sizes, int n_in,
                              void* d_out, int out_size, void* d_ws, size_t ws_size,
                              hipStream_t stream)
{
  const float* x_in   = (const float*)d_in[0];   // [2048,50,384]
  const float* maskp  = (const float*)d_in[1];   // [2048,50,50]
  const float* g0 = (const float*)d_in[2];  const float* b0 = (const float*)d_in[3];
  const float* g1 = (const float*)d_in[4];  const float* b1 = (const float*)d_in[5];
  const float* g2 = (const float*)d_in[6];  const float* b2 = (const float*)d_in[7];
  const float* ge = (const float*)d_in[8];  const float* be = (const float*)d_in[9];
  const float* w_qkv = (const float*)d_in[10];
  const float* w_proj= (const float*)d_in[11];
  const float* b_proj= (const float*)d_in[12];
  const float* rel_pos=(const float*)d_in[13];
  const float* w_fc1 = (const float*)d_in[14];
  const float* b_fc1 = (const float*)d_in[15];
  const float* w_fc2 = (const float*)d_in[16];
  const float* b_fc2 = (const float*)d_in[17];
  const float* w_exp = (const float*)d_in[18];
  const float* b_exp = (const float*)d_in[19];
  const float* w_lin = (const float*)d_in[20];
  const float* b_lin = (const float*)d_in[21];
  float* dout = (float*)d_out;

  const size_t NT = (size_t)NWIN * NTOK;   // 102400 tokens

  size_t off = 0;
  auto alloc = [&](size_t bytes)->void* {
    void* p = (char*)d_ws + off;
    off += (bytes + 255) & ~(size_t)255;
    return p;
  };

  bf16* wqkv_b = (bf16*)alloc((size_t)QKVD*CDIM*2);
  bf16* wproj_b= (bf16*)alloc((size_t)CDIM*CDIM*2);
  bf16* wfc1_b = (bf16*)alloc((size_t)MLPH*CDIM*2);
  bf16* wfc2_b = (bf16*)alloc((size_t)DHID*MLPH*2);
  bf16* wexp_b = (bf16*)alloc((size_t)DHID*CDIM*2);
  bf16* wlin_b = (bf16*)alloc((size_t)CDIM*DHID*2);
  float* xb    = (float*)alloc(NT*CDIM*4);
  bf16* clsln  = (bf16*)alloc((size_t)NWIN*CDIM*2);
  float* qkvcls= (float*)alloc((size_t)NWIN*QKVD*4);
  bf16* ycls   = (bf16*)alloc((size_t)NWIN*CDIM*2);

  // chunk size in windows (tokens must stay multiple of 128 -> windows multiple of 64)
  int CH_W = 256;
  const size_t per_window = 50ull*(CDIM*2 + QKVD*4 + CDIM*2 + DHID*4 + MLPH*2 + DHID*2); // 844800
  while (CH_W > 64 && off + (size_t)CH_W*per_window + 8192 > ws_size) CH_W >>= 1;
  const int CH_T = CH_W * NTOK;

  bf16*  xln  = (bf16*) alloc((size_t)CH_T*CDIM*2);
  float* qkvc = (float*)alloc((size_t)CH_T*QKVD*4);
  bf16*  ybfc = (bf16*) alloc((size_t)CH_T*CDIM*2);
  float* idc  = (float*)alloc((size_t)CH_T*DHID*4);
  bf16*  h1c  = (bf16*) alloc((size_t)CH_T*MLPH*2);
  bf16*  tmpc = (bf16*) alloc((size_t)CH_T*DHID*2);

  // ---- weights to bf16 ----
  cvt_bf16_kernel<<<256, 256, 0, stream>>>(w_qkv,  wqkv_b,  QKVD*CDIM);
  cvt_bf16_kernel<<<256, 256, 0, stream>>>(w_proj, wproj_b, CDIM*CDIM);
  cvt_bf16_kernel<<<256, 256, 0, stream>>>(w_fc1,  wfc1_b,  MLPH*CDIM);
  cvt_bf16_kernel<<<256, 256, 0, stream>>>(w_fc2,  wfc2_b,  DHID*MLPH);
  cvt_bf16_kernel<<<256, 256, 0, stream>>>(w_exp,  wexp_b,  DHID*CDIM);
  cvt_bf16_kernel<<<256, 256, 0, stream>>>(w_lin,  wlin_b,  CDIM*DHID);

  // ---- xb = input copy (residual stream, fp32) ----
  hipMemcpyAsync(xb, x_in, NT*CDIM*4, hipMemcpyDeviceToDevice, stream);

  // ---- cls path ----
  ln_kernel<false><<<NWIN/4, 256, 0, stream>>>(x_in, (long)NTOK*CDIM, g0, b0, clsln, NWIN);
  gemm_bt<false,false,false,false><<<dim3(QKVD/128, NWIN/128), 256, 0, stream>>>(
      clsln, wqkv_b, qkvcls, nullptr, nullptr, NWIN, QKVD, CDIM, QKVD, 0);
  attn_cls_kernel<<<dim3(IMGS, NHEADS), 256, 0, stream>>>(qkvcls, ycls);
  gemm_bt<false,true,true,false><<<dim3(CDIM/128, NWIN/128), 256, 0, stream>>>(
      ycls, wproj_b, xb, b_proj, x_in, NWIN, CDIM, CDIM, NTOK*CDIM, NTOK*CDIM);

  // ---- main chunk loop ----
  const int nch = NWIN / CH_W;
  for (int c = 0; c < nch; c++){
    int w0 = c * CH_W;
    size_t t0 = (size_t)w0 * NTOK;
    float* xbc = xb + t0*CDIM;
    int MT = CH_T, MB = CH_T/128;

    // window attention
    ln_kernel<false><<<MT/4, 256, 0, stream>>>(xbc, CDIM, g1, b1, xln, MT);
    gemm_bt<false,false,false,false><<<dim3(QKVD/128, MB), 256, 0, stream>>>(
        xln, wqkv_b, qkvc, nullptr, nullptr, MT, QKVD, CDIM, QKVD, 0);
    attn_win_kernel<<<dim3(CH_W, NHEADS), 256, 0, stream>>>(qkvc, maskp, rel_pos, ybfc, w0);
    gemm_bt<false,true,true,false><<<dim3(CDIM/128, MB), 256, 0, stream>>>(
        ybfc, wproj_b, xbc, b_proj, xbc, MT, CDIM, CDIM, CDIM, CDIM);

    // expand path: identity = gelu(LN(x)) @ w_exp^T + b_exp
    ln_kernel<true><<<MT/4, 256, 0, stream>>>(xbc, CDIM, ge, be, xln, MT);
    gemm_bt<false,true,false,false><<<dim3(DHID/128, MB), 256, 0, stream>>>(
        xln, wexp_b, idc, b_exp, nullptr, MT, DHID, CDIM, DHID, 0);

    // mlp path
    ln_kernel<false><<<MT/4, 256, 0, stream>>>(xbc, CDIM, g2, b2, xln, MT);
    gemm_bt<true,true,false,true><<<dim3(MLPH/128, MB), 256, 0, stream>>>(
        xln, wfc1_b, h1c, b_fc1, nullptr, MT, MLPH, CDIM, MLPH, 0);
    gemm_bt<true,true,true,false><<<dim3(DHID/128, MB), 256, 0, stream>>>(
        h1c, wfc2_b, tmpc, b_fc2, idc, MT, DHID, MLPH, DHID, DHID);

    // final projection -> d_out
    gemm_bt<false,true,false,false><<<dim3(CDIM/128, MB), 256, 0, stream>>>(
        tmpc, wlin_b, dout + t0*CDIM, b_lin, nullptr, MT, CDIM, DHID, CDIM, 0);
  }
}

// Round 2
// 3338.934 us; speedup vs baseline: 1.0255x; 1.0255x over previous
//
#include <hip/hip_runtime.h>
#include <hip/hip_bf16.h>
#include <math.h>

#define NHEADS 12
#define NTOK   50
#define NWIN   2048
#define IMGS   32
#define CDIM   384
#define QKVD   1152
#define DHID   768
#define MLPH   3072
#define SCALE_F 0.17677669529663687f

typedef short short8 __attribute__((ext_vector_type(8)));
typedef float f32x4  __attribute__((ext_vector_type(4)));
typedef __hip_bfloat16 bf16;

__device__ __forceinline__ float gelu_f(float x){
  return 0.5f*x*(1.0f+erff(x*0.7071067811865476f));
}

// ---------------- weight fp32 -> bf16 ----------------
__global__ void cvt_bf16_kernel(const float* __restrict__ x, bf16* __restrict__ y, int n){
  for (int i = blockIdx.x*blockDim.x + threadIdx.x; i < n; i += gridDim.x*blockDim.x)
    y[i] = __float2bfloat16(x[i]);
}

// ---------------- LayerNorm (optionally fused GELU), fp32 in -> bf16 out ----------------
template<bool GELU>
__global__ __launch_bounds__(256) void ln_kernel(const float* __restrict__ x, long ldx,
    const float* __restrict__ g, const float* __restrict__ b,
    bf16* __restrict__ y, int rows)
{
  int row = blockIdx.x*4 + (threadIdx.x>>6);
  if (row >= rows) return;
  int l = threadIdx.x & 63;
  const float* xr = x + (size_t)row*ldx;
  float v[6]; float s = 0.f;
  #pragma unroll
  for (int j=0;j<6;j++){ v[j] = xr[l + 64*j]; s += v[j]; }
  #pragma unroll
  for (int off=32; off; off>>=1) s += __shfl_xor(s, off, 64);
  float mean = s * (1.0f/384.0f);
  float vs = 0.f;
  #pragma unroll
  for (int j=0;j<6;j++){ float d = v[j]-mean; vs += d*d; }
  #pragma unroll
  for (int off=32; off; off>>=1) vs += __shfl_xor(vs, off, 64);
  float rstd = rsqrtf(vs*(1.0f/384.0f) + 1e-5f);
  bf16* yr = y + (size_t)row*384;
  #pragma unroll
  for (int j=0;j<6;j++){
    float o = (v[j]-mean)*rstd*g[l+64*j] + b[l+64*j];
    if (GELU) o = gelu_f(o);
    yr[l + 64*j] = __float2bfloat16(o);
  }
}

// ---------------- GEMM: C[M,N] = A[M,K](bf16) * W[N,K]^T(bf16), fp32 acc ----------------
// 128x128 tile, 4 waves, 16x16x32 MFMA, global_load_lds width-16 staging (m97 structure).
// M%128==0, N%128==0, K%32==0 required.
template<bool OUT_BF16, bool BIAS, bool RES, bool GELU>
__global__ __launch_bounds__(256) void gemm_bt(
    const bf16* __restrict__ A, const bf16* __restrict__ B, void* __restrict__ Cv,
    const float* __restrict__ bias, const float* __restrict__ res,
    int M, int N, int K, int ldc, int ldres)
{
  __shared__ short As[128*32];
  __shared__ short Bs[128*32];
  const int t  = threadIdx.x;
  const int l  = t & 63;
  const int w  = t >> 6;
  const int wr = w >> 1, wc = w & 1;
  const int lr = l & 15, kg = l >> 4;
  const int bm = blockIdx.y * 128, bn = blockIdx.x * 128;
  const short* Ag = (const short*)A;
  const short* Bg = (const short*)B;

  // staging geometry: wave w, issue p in {0,1}: LDS bytes [(w*2+p)*1024 + lane*16)
  // element offset (shorts): eo = (w*2+p)*512 + l*8 ; row = eo>>5, col = eo&31
  const int eo0 = w*1024 + l*8;
  const int rowA0 = eo0 >> 5, colA0 = eo0 & 31;
  const int eo1 = eo0 + 512;
  const int rowA1 = eo1 >> 5, colA1 = eo1 & 31;

  f32x4 acc[4][4] = {};

  for (int k0 = 0; k0 < K; k0 += 32) {
    __builtin_amdgcn_global_load_lds(
      (const __attribute__((address_space(1))) void*)&Ag[(size_t)(bm+rowA0)*K + k0 + colA0],
      (__attribute__((address_space(3))) void*)((char*)As + w*2048), 16, 0, 0);
    __builtin_amdgcn_global_load_lds(
      (const __attribute__((address_space(1))) void*)&Bg[(size_t)(bn+rowA0)*K + k0 + colA0],
      (__attribute__((address_space(3))) void*)((char*)Bs + w*2048), 16, 0, 0);
    __builtin_amdgcn_global_load_lds(
      (const __attribute__((address_space(1))) void*)&Ag[(size_t)(bm+rowA1)*K + k0 + colA1],
      (__attribute__((address_space(3))) void*)((char*)As + w*2048 + 1024), 16, 0, 0);
    __builtin_amdgcn_global_load_lds(
      (const __attribute__((address_space(1))) void*)&Bg[(size_t)(bn+rowA1)*K + k0 + colA1],
      (__attribute__((address_space(3))) void*)((char*)Bs + w*2048 + 1024), 16, 0, 0);
    __syncthreads();
    short8 af[4], bfm[4];
    #pragma unroll
    for (int m=0;m<4;m++) af[m]  = *(const short8*)(&As[(wr*64 + m*16 + lr)*32 + kg*8]);
    #pragma unroll
    for (int n=0;n<4;n++) bfm[n] = *(const short8*)(&Bs[(wc*64 + n*16 + lr)*32 + kg*8]);
    #pragma unroll
    for (int m=0;m<4;m++)
      #pragma unroll
      for (int n=0;n<4;n++)
        acc[m][n] = __builtin_amdgcn_mfma_f32_16x16x32_bf16(af[m], bfm[n], acc[m][n], 0,0,0);
    __syncthreads();
  }

  #pragma unroll
  for (int m=0;m<4;m++){
    int row0 = bm + wr*64 + m*16 + kg*4;
    #pragma unroll
    for (int n=0;n<4;n++){
      int col = bn + wc*64 + n*16 + lr;
      float bv = BIAS ? bias[col] : 0.0f;
      #pragma unroll
      for (int r=0;r<4;r++){
        float val = acc[m][n][r] + bv;
        if (RES)  val += res[(size_t)(row0+r)*ldres + col];
        if (GELU) val = gelu_f(val);
        if (OUT_BF16) ((bf16*)Cv)[(size_t)(row0+r)*ldc + col] = __float2bfloat16(val);
        else          ((float*)Cv)[(size_t)(row0+r)*ldc + col] = val;
      }
    }
  }
}

// ---------------- cls attention: 32 images x 64 window-tokens, 12 heads, d=32 ----------------
__global__ __launch_bounds__(256) void attn_cls_kernel(const bf16* __restrict__ qkv,
                                                       bf16* __restrict__ y)
{
  int img = blockIdx.x, h = blockIdx.y;
  __shared__ float q[64][33], k[64][33], v[64][33];
  __shared__ float s[64][65];
  int t = threadIdx.x;
  for (int idx=t; idx<64*32; idx+=256){
    int i = idx>>5, d = idx&31;
    const bf16* base = qkv + ((size_t)(img*64+i))*QKVD + h*32 + d;
    q[i][d] = __bfloat162float(base[0]);
    k[i][d] = __bfloat162float(base[384]);
    v[i][d] = __bfloat162float(base[768]);
  }
  __syncthreads();
  for (int idx=t; idx<64*64; idx+=256){
    int i = idx>>6, j = idx&63;
    float a = 0.f;
    #pragma unroll
    for (int d=0; d<32; d++) a += q[i][d]*k[j][d];
    s[i][j] = a * SCALE_F;
  }
  __syncthreads();
  if (t < 64){
    float m = -1e30f;
    for (int j=0;j<64;j++) m = fmaxf(m, s[t][j]);
    float sum = 0.f;
    for (int j=0;j<64;j++){ float e = __expf(s[t][j]-m); s[t][j]=e; sum+=e; }
    float inv = 1.0f/sum;
    for (int j=0;j<64;j++) s[t][j] *= inv;
  }
  __syncthreads();
  for (int idx=t; idx<64*32; idx+=256){
    int i = idx>>5, d = idx&31;
    float a = 0.f;
    for (int j=0;j<64;j++) a += s[i][j]*v[j][d];
    y[((size_t)(img*64+i))*CDIM + h*32 + d] = __float2bfloat16(a);
  }
}

// ---------------- window attention: 50 tokens, rel-pos bias on [1:,1:], + mask ----------------
__global__ __launch_bounds__(256) void attn_win_kernel(const bf16* __restrict__ qkv,
    const float* __restrict__ mask, const float* __restrict__ rel_pos,
    bf16* __restrict__ y, int win0)
{
  int lw = blockIdx.x, h = blockIdx.y;
  int wgl = win0 + lw;
  __shared__ float q[50][33], k[50][33], v[50][33];
  __shared__ float s[50][51];
  __shared__ float rp[169];
  int t = threadIdx.x;
  for (int idx=t; idx<50*32; idx+=256){
    int i = idx>>5, d = idx&31;
    const bf16* base = qkv + ((size_t)(lw*50+i))*QKVD + h*32 + d;
    q[i][d] = __bfloat162float(base[0]);
    k[i][d] = __bfloat162float(base[384]);
    v[i][d] = __bfloat162float(base[768]);
  }
  for (int idx=t; idx<169; idx+=256) rp[idx] = rel_pos[idx*NHEADS + h];
  __syncthreads();
  const float* mrow = mask + (size_t)wgl*2500;
  for (int idx=t; idx<2500; idx+=256){
    int i = idx/50, j = idx - i*50;
    float a = 0.f;
    #pragma unroll
    for (int d=0; d<32; d++) a += q[i][d]*k[j][d];
    a *= SCALE_F;
    if (i > 0 && j > 0){
      int qi = i-1, kj = j-1;
      int ridx = ((qi/7)-(kj/7)+6)*13 + ((qi%7)-(kj%7)+6);
      a += rp[ridx];
    }
    a += mrow[idx];
    s[i][j] = a;
  }
  __syncthreads();
  if (t < 50){
    float m = -1e30f;
    for (int j=0;j<50;j++) m = fmaxf(m, s[t][j]);
    float sum = 0.f;
    for (int j=0;j<50;j++){ float e = __expf(s[t][j]-m); s[t][j]=e; sum+=e; }
    float inv = 1.0f/sum;
    for (int j=0;j<50;j++) s[t][j] *= inv;
  }
  __syncthreads();
  for (int idx=t; idx<50*32; idx+=256){
    int i = idx>>5, d = idx&31;
    float a = 0.f;
    for (int j=0;j<50;j++) a += s[i][j]*v[j][d];
    y[((size_t)(lw*50+i))*CDIM + h*32 + d] = __float2bfloat16(a);
  }
}

// ---------------------------------------------------------------------------
extern "C" void kernel_launch(void* const* d_in, const int* in_sizes, int n_in,
                              void* d_out, int out_size, void* d_ws, size_t ws_size,
                              hipStream_t stream)
{
  const float* x_in   = (const float*)d_in[0];   // [2048,50,384]
  const float* maskp  = (const float*)d_in[1];   // [2048,50,50]
  const float* g0 = (const float*)d_in[2];  const float* b0 = (const float*)d_in[3];
  const float* g1 = (const float*)d_in[4];  const float* b1 = (const float*)d_in[5];
  const float* g2 = (const float*)d_in[6];  const float* b2 = (const float*)d_in[7];
  const float* ge = (const float*)d_in[8];  const float* be = (const float*)d_in[9];
  const float* w_qkv = (const float*)d_in[10];
  const float* w_proj= (const float*)d_in[11];
  const float* b_proj= (const float*)d_in[12];
  const float* rel_pos=(const float*)d_in[13];
  const float* w_fc1 = (const float*)d_in[14];
  const float* b_fc1 = (const float*)d_in[15];
  const float* w_fc2 = (const float*)d_in[16];
  const float* b_fc2 = (const float*)d_in[17];
  const float* w_exp = (const float*)d_in[18];
  const float* b_exp = (const float*)d_in[19];
  const float* w_lin = (const float*)d_in[20];
  const float* b_lin = (const float*)d_in[21];
  float* dout = (float*)d_out;

  const size_t NT = (size_t)NWIN * NTOK;   // 102400 tokens

  size_t off = 0;
  auto alloc = [&](size_t bytes)->void* {
    void* p = (char*)d_ws + off;
    off += (bytes + 255) & ~(size_t)255;
    return p;
  };

  bf16* wqkv_b = (bf16*)alloc((size_t)QKVD*CDIM*2);
  bf16* wproj_b= (bf16*)alloc((size_t)CDIM*CDIM*2);
  bf16* wfc1_b = (bf16*)alloc((size_t)MLPH*CDIM*2);
  bf16* wfc2_b = (bf16*)alloc((size_t)DHID*MLPH*2);
  bf16* wexp_b = (bf16*)alloc((size_t)DHID*CDIM*2);
  bf16* wlin_b = (bf16*)alloc((size_t)CDIM*DHID*2);
  float* xb    = (float*)alloc(NT*CDIM*4);
  bf16* clsln  = (bf16*)alloc((size_t)NWIN*CDIM*2);
  bf16* qkvcls = (bf16*)alloc((size_t)NWIN*QKVD*2);
  bf16* ycls   = (bf16*)alloc((size_t)NWIN*CDIM*2);

  // chunk size in windows (tokens must stay multiple of 128 -> windows multiple of 64)
  int CH_W = 256;
  const size_t per_window = 50ull*(CDIM*2 + QKVD*2 + CDIM*2 + DHID*4 + MLPH*2 + DHID*2);
  while (CH_W > 64 && off + (size_t)CH_W*per_window + 8192 > ws_size) CH_W >>= 1;
  const int CH_T = CH_W * NTOK;

  bf16*  xln  = (bf16*) alloc((size_t)CH_T*CDIM*2);
  bf16*  qkvc = (bf16*) alloc((size_t)CH_T*QKVD*2);
  bf16*  ybfc = (bf16*) alloc((size_t)CH_T*CDIM*2);
  float* idc  = (float*)alloc((size_t)CH_T*DHID*4);
  bf16*  h1c  = (bf16*) alloc((size_t)CH_T*MLPH*2);
  bf16*  tmpc = (bf16*) alloc((size_t)CH_T*DHID*2);

  // ---- weights to bf16 ----
  cvt_bf16_kernel<<<256, 256, 0, stream>>>(w_qkv,  wqkv_b,  QKVD*CDIM);
  cvt_bf16_kernel<<<256, 256, 0, stream>>>(w_proj, wproj_b, CDIM*CDIM);
  cvt_bf16_kernel<<<256, 256, 0, stream>>>(w_fc1,  wfc1_b,  MLPH*CDIM);
  cvt_bf16_kernel<<<256, 256, 0, stream>>>(w_fc2,  wfc2_b,  DHID*MLPH);
  cvt_bf16_kernel<<<256, 256, 0, stream>>>(w_exp,  wexp_b,  DHID*CDIM);
  cvt_bf16_kernel<<<256, 256, 0, stream>>>(w_lin,  wlin_b,  CDIM*DHID);

  // ---- xb = input copy (residual stream, fp32) ----
  hipMemcpyAsync(xb, x_in, NT*CDIM*4, hipMemcpyDeviceToDevice, stream);

  // ---- cls path ----
  ln_kernel<false><<<NWIN/4, 256, 0, stream>>>(x_in, (long)NTOK*CDIM, g0, b0, clsln, NWIN);
  gemm_bt<true,false,false,false><<<dim3(QKVD/128, NWIN/128), 256, 0, stream>>>(
      clsln, wqkv_b, qkvcls, nullptr, nullptr, NWIN, QKVD, CDIM, QKVD, 0);
  attn_cls_kernel<<<dim3(IMGS, NHEADS), 256, 0, stream>>>(qkvcls, ycls);
  gemm_bt<false,true,true,false><<<dim3(CDIM/128, NWIN/128), 256, 0, stream>>>(
      ycls, wproj_b, xb, b_proj, x_in, NWIN, CDIM, CDIM, NTOK*CDIM, NTOK*CDIM);

  // ---- main chunk loop ----
  const int nch = NWIN / CH_W;
  for (int c = 0; c < nch; c++){
    int w0 = c * CH_W;
    size_t t0 = (size_t)w0 * NTOK;
    float* xbc = xb + t0*CDIM;
    int MT = CH_T, MB = CH_T/128;

    // window attention
    ln_kernel<false><<<MT/4, 256, 0, stream>>>(xbc, CDIM, g1, b1, xln, MT);
    gemm_bt<true,false,false,false><<<dim3(QKVD/128, MB), 256, 0, stream>>>(
        xln, wqkv_b, qkvc, nullptr, nullptr, MT, QKVD, CDIM, QKVD, 0);
    attn_win_kernel<<<dim3(CH_W, NHEADS), 256, 0, stream>>>(qkvc, maskp, rel_pos, ybfc, w0);
    gemm_bt<false,true,true,false><<<dim3(CDIM/128, MB), 256, 0, stream>>>(
        ybfc, wproj_b, xbc, b_proj, xbc, MT, CDIM, CDIM, CDIM, CDIM);

    // expand path: identity = gelu(LN(x)) @ w_exp^T + b_exp
    ln_kernel<true><<<MT/4, 256, 0, stream>>>(xbc, CDIM, ge, be, xln, MT);
    gemm_bt<false,true,false,false><<<dim3(DHID/128, MB), 256, 0, stream>>>(
        xln, wexp_b, idc, b_exp, nullptr, MT, DHID, CDIM, DHID, 0);

    // mlp path
    ln_kernel<false><<<MT/4, 256, 0, stream>>>(xbc, CDIM, g2, b2, xln, MT);
    gemm_bt<true,true,false,true><<<dim3(MLPH/128, MB), 256, 0, stream>>>(
        xln, wfc1_b, h1c, b_fc1, nullptr, MT, MLPH, CDIM, MLPH, 0);
    gemm_bt<true,true,true,false><<<dim3(DHID/128, MB), 256, 0, stream>>>(
        h1c, wfc2_b, tmpc, b_fc2, idc, MT, DHID, MLPH, DHID, DHID);

    // final projection -> d_out
    gemm_bt<false,true,false,false><<<dim3(CDIM/128, MB), 256, 0, stream>>>(
        tmpc, wlin_b, dout + t0*CDIM, b_lin, nullptr, MT, CDIM, DHID, CDIM, 0);
  }
}

// Round 3
// 2760.071 us; speedup vs baseline: 1.2405x; 1.2097x over previous
//
#include <hip/hip_runtime.h>
#include <hip/hip_bf16.h>
#include <math.h>

#define NHEADS 12
#define NTOK   50
#define NWIN   2048
#define IMGS   32
#define CDIM   384
#define QKVD   1152
#define DHID   768
#define MLPH   3072
#define SCALE_F 0.17677669529663687f

typedef short short8 __attribute__((ext_vector_type(8)));
typedef float f32x4  __attribute__((ext_vector_type(4)));
typedef __hip_bfloat16 bf16;

__device__ __forceinline__ float gelu_f(float x){
  return 0.5f*x*(1.0f+erff(x*0.7071067811865476f));
}

// ---------------- weight fp32 -> bf16 ----------------
__global__ void cvt_bf16_kernel(const float* __restrict__ x, bf16* __restrict__ y, int n){
  for (int i = blockIdx.x*blockDim.x + threadIdx.x; i < n; i += gridDim.x*blockDim.x)
    y[i] = __float2bfloat16(x[i]);
}

// ---------------- LayerNorm (optionally fused GELU), fp32 in -> bf16 out ----------------
template<bool GELU>
__global__ __launch_bounds__(256) void ln_kernel(const float* __restrict__ x, long ldx,
    const float* __restrict__ g, const float* __restrict__ b,
    bf16* __restrict__ y, int rows)
{
  int row = blockIdx.x*4 + (threadIdx.x>>6);
  if (row >= rows) return;
  int l = threadIdx.x & 63;
  const float* xr = x + (size_t)row*ldx;
  float v[6]; float s = 0.f;
  #pragma unroll
  for (int j=0;j<6;j++){ v[j] = xr[l + 64*j]; s += v[j]; }
  #pragma unroll
  for (int off=32; off; off>>=1) s += __shfl_xor(s, off, 64);
  float mean = s * (1.0f/384.0f);
  float vs = 0.f;
  #pragma unroll
  for (int j=0;j<6;j++){ float d = v[j]-mean; vs += d*d; }
  #pragma unroll
  for (int off=32; off; off>>=1) vs += __shfl_xor(vs, off, 64);
  float rstd = rsqrtf(vs*(1.0f/384.0f) + 1e-5f);
  bf16* yr = y + (size_t)row*384;
  #pragma unroll
  for (int j=0;j<6;j++){
    float o = (v[j]-mean)*rstd*g[l+64*j] + b[l+64*j];
    if (GELU) o = gelu_f(o);
    yr[l + 64*j] = __float2bfloat16(o);
  }
}

// ---------------- GEMM: C[M,N] = A[M,K](bf16) * W[N,K]^T(bf16), fp32 acc ----------------
// 128x128 tile, 4 waves, 16x16x32 MFMA, global_load_lds width-16 staging (m97 structure),
// bijective XCD-chunked block swizzle (m204) with x-fastest order for A-panel L2 reuse.
// M%128==0, N%128==0, K%32==0 required.
template<bool OUT_BF16, bool BIAS, int RES, bool GELU>   // RES: 0=none 1=fp32 2=bf16
__global__ __launch_bounds__(256) void gemm_bt(
    const bf16* __restrict__ A, const bf16* __restrict__ B, void* __restrict__ Cv,
    const float* __restrict__ bias, const void* __restrict__ res,
    int M, int N, int K, int ldc, int ldres)
{
  __shared__ short As[128*32];
  __shared__ short Bs[128*32];
  const int t  = threadIdx.x;
  const int l  = t & 63;
  const int w  = t >> 6;
  const int wr = w >> 1, wc = w & 1;
  const int lr = l & 15, kg = l >> 4;

  // XCD-aware bijective swizzle: HW round-robins linear id % 8 across XCDs.
  // Give each XCD a contiguous range of logical (x-fastest) tile ids.
  const int nwg = gridDim.x * gridDim.y;
  const int lin = blockIdx.y * gridDim.x + blockIdx.x;
  const int q8 = nwg >> 3, r8 = nwg & 7;
  const int xcd = lin & 7, slot = lin >> 3;
  const int swz = (xcd < r8) ? (xcd*(q8+1) + slot) : (r8*(q8+1) + (xcd-r8)*q8 + slot);
  const int by = swz / gridDim.x, bx = swz - by*gridDim.x;

  const int bm = by * 128, bn = bx * 128;
  const short* Ag = (const short*)A;
  const short* Bg = (const short*)B;

  // staging: wave w, issue p in {0,1}: LDS bytes [(w*2+p)*1024 + lane*16)
  const int eo0 = w*1024 + l*8;
  const int rowA0 = eo0 >> 5, colA0 = eo0 & 31;
  const int eo1 = eo0 + 512;
  const int rowA1 = eo1 >> 5, colA1 = eo1 & 31;

  f32x4 acc[4][4] = {};

  for (int k0 = 0; k0 < K; k0 += 32) {
    __builtin_amdgcn_global_load_lds(
      (const __attribute__((address_space(1))) void*)&Ag[(size_t)(bm+rowA0)*K + k0 + colA0],
      (__attribute__((address_space(3))) void*)((char*)As + w*2048), 16, 0, 0);
    __builtin_amdgcn_global_load_lds(
      (const __attribute__((address_space(1))) void*)&Bg[(size_t)(bn+rowA0)*K + k0 + colA0],
      (__attribute__((address_space(3))) void*)((char*)Bs + w*2048), 16, 0, 0);
    __builtin_amdgcn_global_load_lds(
      (const __attribute__((address_space(1))) void*)&Ag[(size_t)(bm+rowA1)*K + k0 + colA1],
      (__attribute__((address_space(3))) void*)((char*)As + w*2048 + 1024), 16, 0, 0);
    __builtin_amdgcn_global_load_lds(
      (const __attribute__((address_space(1))) void*)&Bg[(size_t)(bn+rowA1)*K + k0 + colA1],
      (__attribute__((address_space(3))) void*)((char*)Bs + w*2048 + 1024), 16, 0, 0);
    __syncthreads();
    short8 af[4], bfm[4];
    #pragma unroll
    for (int m=0;m<4;m++) af[m]  = *(const short8*)(&As[(wr*64 + m*16 + lr)*32 + kg*8]);
    #pragma unroll
    for (int n=0;n<4;n++) bfm[n] = *(const short8*)(&Bs[(wc*64 + n*16 + lr)*32 + kg*8]);
    #pragma unroll
    for (int m=0;m<4;m++)
      #pragma unroll
      for (int n=0;n<4;n++)
        acc[m][n] = __builtin_amdgcn_mfma_f32_16x16x32_bf16(af[m], bfm[n], acc[m][n], 0,0,0);
    __syncthreads();
  }

  #pragma unroll
  for (int m=0;m<4;m++){
    int row0 = bm + wr*64 + m*16 + kg*4;
    #pragma unroll
    for (int n=0;n<4;n++){
      int col = bn + wc*64 + n*16 + lr;
      float bv = BIAS ? bias[col] : 0.0f;
      #pragma unroll
      for (int r=0;r<4;r++){
        float val = acc[m][n][r] + bv;
        if (RES == 1) val += ((const float*)res)[(size_t)(row0+r)*ldres + col];
        if (RES == 2) val += __bfloat162float(((const bf16*)res)[(size_t)(row0+r)*ldres + col]);
        if (GELU) val = gelu_f(val);
        if (OUT_BF16) ((bf16*)Cv)[(size_t)(row0+r)*ldc + col] = __float2bfloat16(val);
        else          ((float*)Cv)[(size_t)(row0+r)*ldc + col] = val;
      }
    }
  }
}

// ---------------- cls attention: 32 images x 64 window-tokens, 12 heads, d=32 ----------------
__global__ __launch_bounds__(256) void attn_cls_kernel(const bf16* __restrict__ qkv,
                                                       bf16* __restrict__ y)
{
  int img = blockIdx.x, h = blockIdx.y;
  __shared__ float q[64][33], k[64][33], v[64][33];
  __shared__ float s[64][65];
  int t = threadIdx.x;
  for (int idx=t; idx<64*32; idx+=256){
    int i = idx>>5, d = idx&31;
    const bf16* base = qkv + ((size_t)(img*64+i))*QKVD + h*32 + d;
    q[i][d] = __bfloat162float(base[0]);
    k[i][d] = __bfloat162float(base[384]);
    v[i][d] = __bfloat162float(base[768]);
  }
  __syncthreads();
  for (int idx=t; idx<64*64; idx+=256){
    int i = idx>>6, j = idx&63;
    float a = 0.f;
    #pragma unroll
    for (int d=0; d<32; d++) a += q[i][d]*k[j][d];
    s[i][j] = a * SCALE_F;
  }
  __syncthreads();
  if (t < 64){
    float m = -1e30f;
    for (int j=0;j<64;j++) m = fmaxf(m, s[t][j]);
    float sum = 0.f;
    for (int j=0;j<64;j++){ float e = __expf(s[t][j]-m); s[t][j]=e; sum+=e; }
    float inv = 1.0f/sum;
    for (int j=0;j<64;j++) s[t][j] *= inv;
  }
  __syncthreads();
  for (int idx=t; idx<64*32; idx+=256){
    int i = idx>>5, d = idx&31;
    float a = 0.f;
    for (int j=0;j<64;j++) a += s[i][j]*v[j][d];
    y[((size_t)(img*64+i))*CDIM + h*32 + d] = __float2bfloat16(a);
  }
}

// ---------------- window attention: 50 tokens, rel-pos bias on [1:,1:], + mask ----------------
__global__ __launch_bounds__(256) void attn_win_kernel(const bf16* __restrict__ qkv,
    const float* __restrict__ mask, const float* __restrict__ rel_pos,
    bf16* __restrict__ y)
{
  int lw = blockIdx.x, h = blockIdx.y;
  __shared__ float q[50][33], k[50][33], v[50][33];
  __shared__ float s[50][51];
  __shared__ float rp[169];
  int t = threadIdx.x;
  for (int idx=t; idx<50*32; idx+=256){
    int i = idx>>5, d = idx&31;
    const bf16* base = qkv + ((size_t)(lw*50+i))*QKVD + h*32 + d;
    q[i][d] = __bfloat162float(base[0]);
    k[i][d] = __bfloat162float(base[384]);
    v[i][d] = __bfloat162float(base[768]);
  }
  for (int idx=t; idx<169; idx+=256) rp[idx] = rel_pos[idx*NHEADS + h];
  __syncthreads();
  const float* mrow = mask + (size_t)lw*2500;
  for (int idx=t; idx<2500; idx+=256){
    int i = idx/50, j = idx - i*50;
    float a = 0.f;
    #pragma unroll
    for (int d=0; d<32; d++) a += q[i][d]*k[j][d];
    a *= SCALE_F;
    if (i > 0 && j > 0){
      int qi = i-1, kj = j-1;
      int ridx = ((qi/7)-(kj/7)+6)*13 + ((qi%7)-(kj%7)+6);
      a += rp[ridx];
    }
    a += mrow[idx];
    s[i][j] = a;
  }
  __syncthreads();
  if (t < 50){
    float m = -1e30f;
    for (int j=0;j<50;j++) m = fmaxf(m, s[t][j]);
    float sum = 0.f;
    for (int j=0;j<50;j++){ float e = __expf(s[t][j]-m); s[t][j]=e; sum+=e; }
    float inv = 1.0f/sum;
    for (int j=0;j<50;j++) s[t][j] *= inv;
  }
  __syncthreads();
  for (int idx=t; idx<50*32; idx+=256){
    int i = idx>>5, d = idx&31;
    float a = 0.f;
    for (int j=0;j<50;j++) a += s[i][j]*v[j][d];
    y[((size_t)(lw*50+i))*CDIM + h*32 + d] = __float2bfloat16(a);
  }
}

// ---------------------------------------------------------------------------
extern "C" void kernel_launch(void* const* d_in, const int* in_sizes, int n_in,
                              void* d_out, int out_size, void* d_ws, size_t ws_size,
                              hipStream_t stream)
{
  const float* x_in   = (const float*)d_in[0];   // [2048,50,384]
  const float* maskp  = (const float*)d_in[1];   // [2048,50,50]
  const float* g0 = (const float*)d_in[2];  const float* b0 = (const float*)d_in[3];
  const float* g1 = (const float*)d_in[4];  const float* b1 = (const float*)d_in[5];
  const float* g2 = (const float*)d_in[6];  const float* b2 = (const float*)d_in[7];
  const float* ge = (const float*)d_in[8];  const float* be = (const float*)d_in[9];
  const float* w_qkv = (const float*)d_in[10];
  const float* w_proj= (const float*)d_in[11];
  const float* b_proj= (const float*)d_in[12];
  const float* rel_pos=(const float*)d_in[13];
  const float* w_fc1 = (const float*)d_in[14];
  const float* b_fc1 = (const float*)d_in[15];
  const float* w_fc2 = (const float*)d_in[16];
  const float* b_fc2 = (const float*)d_in[17];
  const float* w_exp = (const float*)d_in[18];
  const float* b_exp = (const float*)d_in[19];
  const float* w_lin = (const float*)d_in[20];
  const float* b_lin = (const float*)d_in[21];
  float* dout = (float*)d_out;

  const size_t NT = (size_t)NWIN * NTOK;   // 102400 tokens

  size_t off = 0;
  auto alloc = [&](size_t bytes)->void* {
    void* p = (char*)d_ws + off;
    off += (bytes + 255) & ~(size_t)255;
    return p;
  };

  bf16* wqkv_b = (bf16*)alloc((size_t)QKVD*CDIM*2);
  bf16* wproj_b= (bf16*)alloc((size_t)CDIM*CDIM*2);
  bf16* wfc1_b = (bf16*)alloc((size_t)MLPH*CDIM*2);
  bf16* wfc2_b = (bf16*)alloc((size_t)DHID*MLPH*2);
  bf16* wexp_b = (bf16*)alloc((size_t)DHID*CDIM*2);
  bf16* wlin_b = (bf16*)alloc((size_t)CDIM*DHID*2);
  float* xb    = (float*)alloc(NT*CDIM*4);
  bf16* clsln  = (bf16*)alloc((size_t)NWIN*CDIM*2);
  bf16* qkvcls = (bf16*)alloc((size_t)NWIN*QKVD*2);
  bf16* ycls   = (bf16*)alloc((size_t)NWIN*CDIM*2);

  // chunk size in windows; try all-at-once first, halve until workspace fits.
  // per-window bytes: xln 38400 + qkvc 115200 + ybfc 38400 + idc(bf16) 76800
  //                   + h1c 307200 + tmpc 76800 = 652800
  int CH_W = 2048;
  const size_t per_window = 652800ull;
  while (CH_W > 64 && off + (size_t)CH_W*per_window + 16384 > ws_size) CH_W >>= 1;
  const int CH_T = CH_W * NTOK;

  bf16*  xln  = (bf16*) alloc((size_t)CH_T*CDIM*2);
  bf16*  qkvc = (bf16*) alloc((size_t)CH_T*QKVD*2);
  bf16*  ybfc = (bf16*) alloc((size_t)CH_T*CDIM*2);
  bf16*  idc  = (bf16*) alloc((size_t)CH_T*DHID*2);
  bf16*  h1c  = (bf16*) alloc((size_t)CH_T*MLPH*2);
  bf16*  tmpc = (bf16*) alloc((size_t)CH_T*DHID*2);

  // ---- weights to bf16 ----
  cvt_bf16_kernel<<<256, 256, 0, stream>>>(w_qkv,  wqkv_b,  QKVD*CDIM);
  cvt_bf16_kernel<<<256, 256, 0, stream>>>(w_proj, wproj_b, CDIM*CDIM);
  cvt_bf16_kernel<<<256, 256, 0, stream>>>(w_fc1,  wfc1_b,  MLPH*CDIM);
  cvt_bf16_kernel<<<256, 256, 0, stream>>>(w_fc2,  wfc2_b,  DHID*MLPH);
  cvt_bf16_kernel<<<256, 256, 0, stream>>>(w_exp,  wexp_b,  DHID*CDIM);
  cvt_bf16_kernel<<<256, 256, 0, stream>>>(w_lin,  wlin_b,  CDIM*DHID);

  // ---- xb = input copy (residual stream, fp32) ----
  hipMemcpyAsync(xb, x_in, NT*CDIM*4, hipMemcpyDeviceToDevice, stream);

  // ---- cls path ----
  ln_kernel<false><<<NWIN/4, 256, 0, stream>>>(x_in, (long)NTOK*CDIM, g0, b0, clsln, NWIN);
  gemm_bt<true,false,0,false><<<dim3(QKVD/128, NWIN/128), 256, 0, stream>>>(
      clsln, wqkv_b, qkvcls, nullptr, nullptr, NWIN, QKVD, CDIM, QKVD, 0);
  attn_cls_kernel<<<dim3(IMGS, NHEADS), 256, 0, stream>>>(qkvcls, ycls);
  gemm_bt<false,true,1,false><<<dim3(CDIM/128, NWIN/128), 256, 0, stream>>>(
      ycls, wproj_b, xb, b_proj, x_in, NWIN, CDIM, CDIM, NTOK*CDIM, NTOK*CDIM);

  // ---- main chunk loop ----
  const int nch = NWIN / CH_W;
  for (int c = 0; c < nch; c++){
    int w0 = c * CH_W;
    size_t t0 = (size_t)w0 * NTOK;
    float* xbc = xb + t0*CDIM;
    int MT = CH_T, MB = CH_T/128;

    // window attention
    ln_kernel<false><<<MT/4, 256, 0, stream>>>(xbc, CDIM, g1, b1, xln, MT);
    gemm_bt<true,false,0,false><<<dim3(QKVD/128, MB), 256, 0, stream>>>(
        xln, wqkv_b, qkvc, nullptr, nullptr, MT, QKVD, CDIM, QKVD, 0);
    attn_win_kernel<<<dim3(CH_W, NHEADS), 256, 0, stream>>>(
        qkvc, maskp + (size_t)w0*2500, rel_pos, ybfc);
    gemm_bt<false,true,1,false><<<dim3(CDIM/128, MB), 256, 0, stream>>>(
        ybfc, wproj_b, xbc, b_proj, xbc, MT, CDIM, CDIM, CDIM, CDIM);

    // expand path: identity = gelu(LN(x)) @ w_exp^T + b_exp  (bf16 out)
    ln_kernel<true><<<MT/4, 256, 0, stream>>>(xbc, CDIM, ge, be, xln, MT);
    gemm_bt<true,true,0,false><<<dim3(DHID/128, MB), 256, 0, stream>>>(
        xln, wexp_b, idc, b_exp, nullptr, MT, DHID, CDIM, DHID, 0);

    // mlp path
    ln_kernel<false><<<MT/4, 256, 0, stream>>>(xbc, CDIM, g2, b2, xln, MT);
    gemm_bt<true,true,0,true><<<dim3(MLPH/128, MB), 256, 0, stream>>>(
        xln, wfc1_b, h1c, b_fc1, nullptr, MT, MLPH, CDIM, MLPH, 0);
    gemm_bt<true,true,2,false><<<dim3(DHID/128, MB), 256, 0, stream>>>(
        h1c, wfc2_b, tmpc, b_fc2, idc, MT, DHID, MLPH, DHID, DHID);

    // final projection -> d_out
    gemm_bt<false,true,0,false><<<dim3(CDIM/128, MB), 256, 0, stream>>>(
        tmpc, wlin_b, dout + t0*CDIM, b_lin, nullptr, MT, CDIM, DHID, CDIM, 0);
  }
}

// Round 4
// 2646.814 us; speedup vs baseline: 1.2936x; 1.0428x over previous
//
#include <hip/hip_runtime.h>
#include <hip/hip_bf16.h>
#include <math.h>

#define NHEADS 12
#define NTOK   50
#define NWIN   2048
#define IMGS   32
#define CDIM   384
#define QKVD   1152
#define DHID   768
#define MLPH   3072
#define SCALE_F 0.17677669529663687f

typedef short short8 __attribute__((ext_vector_type(8)));
typedef short short2v __attribute__((ext_vector_type(2)));
typedef float f32x4  __attribute__((ext_vector_type(4)));
typedef __hip_bfloat16 bf16;

__device__ __forceinline__ float gelu_f(float x){
  return 0.5f*x*(1.0f+erff(x*0.7071067811865476f));
}
__device__ __forceinline__ short bfs(float x){
  bf16 h = __float2bfloat16(x); return *(short*)&h;
}

// ---------------- all weights fp32 -> bf16, one kernel ----------------
__global__ void cvt6_kernel(const float* s0, bf16* d0, int n0,
                            const float* s1, bf16* d1, int n1,
                            const float* s2, bf16* d2, int n2,
                            const float* s3, bf16* d3, int n3,
                            const float* s4, bf16* d4, int n4,
                            const float* s5, bf16* d5, int n5){
  int stride = gridDim.x*blockDim.x, g = blockIdx.x*blockDim.x + threadIdx.x;
  for (int i=g; i<n0; i+=stride) d0[i] = __float2bfloat16(s0[i]);
  for (int i=g; i<n1; i+=stride) d1[i] = __float2bfloat16(s1[i]);
  for (int i=g; i<n2; i+=stride) d2[i] = __float2bfloat16(s2[i]);
  for (int i=g; i<n3; i+=stride) d3[i] = __float2bfloat16(s3[i]);
  for (int i=g; i<n4; i+=stride) d4[i] = __float2bfloat16(s4[i]);
  for (int i=g; i<n5; i+=stride) d5[i] = __float2bfloat16(s5[i]);
}

// ---------------- LayerNorm, fp32 in -> bf16 out (float2 vectorized) ----------------
template<bool GELU>
__global__ __launch_bounds__(256) void ln_kernel(const float* __restrict__ x, long ldx,
    const float* __restrict__ g, const float* __restrict__ b,
    bf16* __restrict__ y, int rows)
{
  int row = blockIdx.x*4 + (threadIdx.x>>6);
  if (row >= rows) return;
  int l = threadIdx.x & 63;
  const float2* xr = (const float2*)(x + (size_t)row*ldx);
  float2 v[3]; float s = 0.f;
  #pragma unroll
  for (int j=0;j<3;j++){ v[j] = xr[l + 64*j]; s += v[j].x + v[j].y; }
  #pragma unroll
  for (int off=32; off; off>>=1) s += __shfl_xor(s, off, 64);
  float mean = s * (1.0f/384.0f);
  float vs = 0.f;
  #pragma unroll
  for (int j=0;j<3;j++){ float dx=v[j].x-mean, dy=v[j].y-mean; vs += dx*dx+dy*dy; }
  #pragma unroll
  for (int off=32; off; off>>=1) vs += __shfl_xor(vs, off, 64);
  float rstd = rsqrtf(vs*(1.0f/384.0f) + 1e-5f);
  short2v* yr = (short2v*)(y + (size_t)row*384);
  const float2* gv = (const float2*)g; const float2* bv = (const float2*)b;
  #pragma unroll
  for (int j=0;j<3;j++){
    float2 gg = gv[l+64*j], bb = bv[l+64*j];
    float o0 = (v[j].x-mean)*rstd*gg.x + bb.x;
    float o1 = (v[j].y-mean)*rstd*gg.y + bb.y;
    if (GELU){ o0 = gelu_f(o0); o1 = gelu_f(o1); }
    short2v pk; pk[0]=bfs(o0); pk[1]=bfs(o1);
    yr[l+64*j] = pk;
  }
}

// ---------------- dual LayerNorm: one read, two outputs (expand-gelu + mlp) ----------
__global__ __launch_bounds__(256) void ln_dual_kernel(const float* __restrict__ x,
    const float* __restrict__ ge, const float* __restrict__ be,
    const float* __restrict__ g2, const float* __restrict__ b2,
    bf16* __restrict__ yeo, bf16* __restrict__ y2o, int rows)
{
  int row = blockIdx.x*4 + (threadIdx.x>>6);
  if (row >= rows) return;
  int l = threadIdx.x & 63;
  const float2* xr = (const float2*)(x + (size_t)row*384);
  float2 v[3]; float s = 0.f;
  #pragma unroll
  for (int j=0;j<3;j++){ v[j] = xr[l + 64*j]; s += v[j].x + v[j].y; }
  #pragma unroll
  for (int off=32; off; off>>=1) s += __shfl_xor(s, off, 64);
  float mean = s * (1.0f/384.0f);
  float vs = 0.f;
  #pragma unroll
  for (int j=0;j<3;j++){ float dx=v[j].x-mean, dy=v[j].y-mean; vs += dx*dx+dy*dy; }
  #pragma unroll
  for (int off=32; off; off>>=1) vs += __shfl_xor(vs, off, 64);
  float rstd = rsqrtf(vs*(1.0f/384.0f) + 1e-5f);
  short2v* ye = (short2v*)(yeo + (size_t)row*384);
  short2v* y2 = (short2v*)(y2o + (size_t)row*384);
  const float2* gev = (const float2*)ge; const float2* bev = (const float2*)be;
  const float2* g2v = (const float2*)g2; const float2* b2v = (const float2*)b2;
  #pragma unroll
  for (int j=0;j<3;j++){
    float n0 = (v[j].x-mean)*rstd, n1 = (v[j].y-mean)*rstd;
    float2 gg = gev[l+64*j], bb = bev[l+64*j];
    short2v pe; pe[0]=bfs(gelu_f(n0*gg.x+bb.x)); pe[1]=bfs(gelu_f(n1*gg.y+bb.y));
    ye[l+64*j] = pe;
    gg = g2v[l+64*j]; bb = b2v[l+64*j];
    short2v p2; p2[0]=bfs(n0*gg.x+bb.x); p2[1]=bfs(n1*gg.y+bb.y);
    y2[l+64*j] = p2;
  }
}

// ---------------- GEMM device body: C[M,N] = A[M,K] * W[N,K]^T, bf16 in fp32 acc ------
// 128x128 tile, 4 waves, 16x16x32 MFMA. Depth-2 prefetch pipeline: 3 LDS buffers,
// counted s_waitcnt vmcnt(4) + raw s_barrier (T3/T4-lite). XCD-bijective swizzle.
// M%128==0, N%128==0, K%64==0 required (K>=128 for prologue; all our K in {384,768,3072}).
template<bool OUT_BF16, bool BIAS, int RES, bool GELU>   // RES: 0=none 1=fp32 2=bf16
__device__ __forceinline__ void gemm_dev(
    const bf16* __restrict__ A, const bf16* __restrict__ B, void* __restrict__ Cv,
    const float* __restrict__ bias, const void* __restrict__ res,
    int M, int N, int K, int ldc, int ldres)
{
  __shared__ short As[3][128*32];
  __shared__ short Bs[3][128*32];
  const int t  = threadIdx.x;
  const int l  = t & 63;
  const int w  = t >> 6;
  const int wr = w >> 1, wc = w & 1;
  const int lr = l & 15, kg = l >> 4;

  const int nwg = gridDim.x * gridDim.y;
  const int lin = blockIdx.y * gridDim.x + blockIdx.x;
  const int q8 = nwg >> 3, r8 = nwg & 7;
  const int xcd = lin & 7, slot = lin >> 3;
  const int swz = (xcd < r8) ? (xcd*(q8+1) + slot) : (r8*(q8+1) + (xcd-r8)*q8 + slot);
  const int by = swz / gridDim.x, bx = swz - by*gridDim.x;

  const int bm = by * 128, bn = bx * 128;
  const short* Ag = (const short*)A;
  const short* Bg = (const short*)B;

  // staging geometry (linear LDS, wave-uniform dest base):
  const int eo0 = w*1024 + l*8;
  const int rowS0 = eo0 >> 5, colS0 = eo0 & 31;
  const int eo1 = eo0 + 512;
  const int rowS1 = eo1 >> 5, colS1 = eo1 & 31;

  #define STAGE(k0, b) do { \
    __builtin_amdgcn_global_load_lds( \
      (const __attribute__((address_space(1))) void*)&Ag[(size_t)(bm+rowS0)*K + (k0) + colS0], \
      (__attribute__((address_space(3))) void*)((char*)&As[b][0] + w*2048), 16, 0, 0); \
    __builtin_amdgcn_global_load_lds( \
      (const __attribute__((address_space(1))) void*)&Bg[(size_t)(bn+rowS0)*K + (k0) + colS0], \
      (__attribute__((address_space(3))) void*)((char*)&Bs[b][0] + w*2048), 16, 0, 0); \
    __builtin_amdgcn_global_load_lds( \
      (const __attribute__((address_space(1))) void*)&Ag[(size_t)(bm+rowS1)*K + (k0) + colS1], \
      (__attribute__((address_space(3))) void*)((char*)&As[b][0] + w*2048 + 1024), 16, 0, 0); \
    __builtin_amdgcn_global_load_lds( \
      (const __attribute__((address_space(1))) void*)&Bg[(size_t)(bn+rowS1)*K + (k0) + colS1], \
      (__attribute__((address_space(3))) void*)((char*)&Bs[b][0] + w*2048 + 1024), 16, 0, 0); \
  } while(0)

  f32x4 acc[4][4] = {};

  // prologue: stage tiles 0 and 1; wait tile0 landed (tile1's 4 loads stay in flight)
  STAGE(0, 0);
  STAGE(32, 1);
  asm volatile("s_waitcnt vmcnt(4)" ::: "memory");
  __builtin_amdgcn_s_barrier();

  int cur = 0, nb = 2;
  for (int k0 = 0; k0 < K; k0 += 32) {
    const bool more = (k0 + 64 < K);
    if (more) STAGE(k0 + 64, nb);

    short8 af[4], bfm[4];
    #pragma unroll
    for (int m=0;m<4;m++) af[m]  = *(const short8*)(&As[cur][(wr*64 + m*16 + lr)*32 + kg*8]);
    #pragma unroll
    for (int n=0;n<4;n++) bfm[n] = *(const short8*)(&Bs[cur][(wc*64 + n*16 + lr)*32 + kg*8]);
    __builtin_amdgcn_s_setprio(1);
    #pragma unroll
    for (int m=0;m<4;m++)
      #pragma unroll
      for (int n=0;n<4;n++)
        acc[m][n] = __builtin_amdgcn_mfma_f32_16x16x32_bf16(af[m], bfm[n], acc[m][n], 0,0,0);
    __builtin_amdgcn_s_setprio(0);

    if (more) { asm volatile("s_waitcnt vmcnt(4)" ::: "memory"); }
    else      { asm volatile("s_waitcnt vmcnt(0)" ::: "memory"); }
    __builtin_amdgcn_s_barrier();
    cur = (cur==2) ? 0 : cur+1;
    nb  = (nb==2)  ? 0 : nb+1;
  }
  #undef STAGE

  #pragma unroll
  for (int m=0;m<4;m++){
    int row0 = bm + wr*64 + m*16 + kg*4;
    #pragma unroll
    for (int n=0;n<4;n++){
      int col = bn + wc*64 + n*16 + lr;
      float bv = BIAS ? bias[col] : 0.0f;
      #pragma unroll
      for (int r=0;r<4;r++){
        float val = acc[m][n][r] + bv;
        if (RES == 1) val += ((const float*)res)[(size_t)(row0+r)*ldres + col];
        if (RES == 2) val += __bfloat162float(((const bf16*)res)[(size_t)(row0+r)*ldres + col]);
        if (GELU) val = gelu_f(val);
        if (OUT_BF16) ((bf16*)Cv)[(size_t)(row0+r)*ldc + col] = __float2bfloat16(val);
        else          ((float*)Cv)[(size_t)(row0+r)*ldc + col] = val;
      }
    }
  }
}

// Distinct kernel names per GEMM for rocprof attribution
#define GEMM_K(NAME, OB, BI, RE, GE) \
__global__ __launch_bounds__(256) void NAME( \
    const bf16* __restrict__ A, const bf16* __restrict__ B, void* __restrict__ Cv, \
    const float* __restrict__ bias, const void* __restrict__ res, \
    int M, int N, int K, int ldc, int ldres){ \
  gemm_dev<OB,BI,RE,GE>(A,B,Cv,bias,res,M,N,K,ldc,ldres); }

GEMM_K(gemm_qkv_k,  true,  false, 0, false)
GEMM_K(gemm_proj_k, false, true,  1, false)
GEMM_K(gemm_exp_k,  true,  true,  0, false)
GEMM_K(gemm_fc1_k,  true,  true,  0, true)
GEMM_K(gemm_fc2_k,  true,  true,  2, false)
GEMM_K(gemm_lin_k,  false, true,  0, false)

// ---------------- cls attention ----------------
__global__ __launch_bounds__(256) void attn_cls_kernel(const bf16* __restrict__ qkv,
                                                       bf16* __restrict__ y)
{
  int img = blockIdx.x, h = blockIdx.y;
  __shared__ float q[64][33], k[64][33], v[64][33];
  __shared__ float s[64][65];
  int t = threadIdx.x;
  for (int idx=t; idx<64*32; idx+=256){
    int i = idx>>5, d = idx&31;
    const bf16* base = qkv + ((size_t)(img*64+i))*QKVD + h*32 + d;
    q[i][d] = __bfloat162float(base[0]);
    k[i][d] = __bfloat162float(base[384]);
    v[i][d] = __bfloat162float(base[768]);
  }
  __syncthreads();
  for (int idx=t; idx<64*64; idx+=256){
    int i = idx>>6, j = idx&63;
    float a = 0.f;
    #pragma unroll
    for (int d=0; d<32; d++) a += q[i][d]*k[j][d];
    s[i][j] = a * SCALE_F;
  }
  __syncthreads();
  if (t < 64){
    float m = -1e30f;
    for (int j=0;j<64;j++) m = fmaxf(m, s[t][j]);
    float sum = 0.f;
    for (int j=0;j<64;j++){ float e = __expf(s[t][j]-m); s[t][j]=e; sum+=e; }
    float inv = 1.0f/sum;
    for (int j=0;j<64;j++) s[t][j] *= inv;
  }
  __syncthreads();
  for (int idx=t; idx<64*32; idx+=256){
    int i = idx>>5, d = idx&31;
    float a = 0.f;
    for (int j=0;j<64;j++) a += s[i][j]*v[j][d];
    y[((size_t)(img*64+i))*CDIM + h*32 + d] = __float2bfloat16(a);
  }
}

// ---------------- window attention ----------------
__global__ __launch_bounds__(256) void attn_win_kernel(const bf16* __restrict__ qkv,
    const float* __restrict__ mask, const float* __restrict__ rel_pos,
    bf16* __restrict__ y)
{
  int lw = blockIdx.x, h = blockIdx.y;
  __shared__ float q[50][33], k[50][33], v[50][33];
  __shared__ float s[50][51];
  __shared__ float rp[169];
  int t = threadIdx.x;
  for (int idx=t; idx<50*32; idx+=256){
    int i = idx>>5, d = idx&31;
    const bf16* base = qkv + ((size_t)(lw*50+i))*QKVD + h*32 + d;
    q[i][d] = __bfloat162float(base[0]);
    k[i][d] = __bfloat162float(base[384]);
    v[i][d] = __bfloat162float(base[768]);
  }
  for (int idx=t; idx<169; idx+=256) rp[idx] = rel_pos[idx*NHEADS + h];
  __syncthreads();
  const float* mrow = mask + (size_t)lw*2500;
  for (int idx=t; idx<2500; idx+=256){
    int i = idx/50, j = idx - i*50;
    float a = 0.f;
    #pragma unroll
    for (int d=0; d<32; d++) a += q[i][d]*k[j][d];
    a *= SCALE_F;
    if (i > 0 && j > 0){
      int qi = i-1, kj = j-1;
      int ridx = ((qi/7)-(kj/7)+6)*13 + ((qi%7)-(kj%7)+6);
      a += rp[ridx];
    }
    a += mrow[idx];
    s[i][j] = a;
  }
  __syncthreads();
  if (t < 50){
    float m = -1e30f;
    for (int j=0;j<50;j++) m = fmaxf(m, s[t][j]);
    float sum = 0.f;
    for (int j=0;j<50;j++){ float e = __expf(s[t][j]-m); s[t][j]=e; sum+=e; }
    float inv = 1.0f/sum;
    for (int j=0;j<50;j++) s[t][j] *= inv;
  }
  __syncthreads();
  for (int idx=t; idx<50*32; idx+=256){
    int i = idx>>5, d = idx&31;
    float a = 0.f;
    for (int j=0;j<50;j++) a += s[i][j]*v[j][d];
    y[((size_t)(lw*50+i))*CDIM + h*32 + d] = __float2bfloat16(a);
  }
}

// ---------------------------------------------------------------------------
extern "C" void kernel_launch(void* const* d_in, const int* in_sizes, int n_in,
                              void* d_out, int out_size, void* d_ws, size_t ws_size,
                              hipStream_t stream)
{
  const float* x_in   = (const float*)d_in[0];
  const float* maskp  = (const float*)d_in[1];
  const float* g0 = (const float*)d_in[2];  const float* b0 = (const float*)d_in[3];
  const float* g1 = (const float*)d_in[4];  const float* b1 = (const float*)d_in[5];
  const float* g2 = (const float*)d_in[6];  const float* b2 = (const float*)d_in[7];
  const float* ge = (const float*)d_in[8];  const float* be = (const float*)d_in[9];
  const float* w_qkv = (const float*)d_in[10];
  const float* w_proj= (const float*)d_in[11];
  const float* b_proj= (const float*)d_in[12];
  const float* rel_pos=(const float*)d_in[13];
  const float* w_fc1 = (const float*)d_in[14];
  const float* b_fc1 = (const float*)d_in[15];
  const float* w_fc2 = (const float*)d_in[16];
  const float* b_fc2 = (const float*)d_in[17];
  const float* w_exp = (const float*)d_in[18];
  const float* b_exp = (const float*)d_in[19];
  const float* w_lin = (const float*)d_in[20];
  const float* b_lin = (const float*)d_in[21];
  float* dout = (float*)d_out;

  const size_t NT = (size_t)NWIN * NTOK;

  size_t off = 0;
  auto alloc = [&](size_t bytes)->void* {
    void* p = (char*)d_ws + off;
    off += (bytes + 255) & ~(size_t)255;
    return p;
  };

  bf16* wqkv_b = (bf16*)alloc((size_t)QKVD*CDIM*2);
  bf16* wproj_b= (bf16*)alloc((size_t)CDIM*CDIM*2);
  bf16* wfc1_b = (bf16*)alloc((size_t)MLPH*CDIM*2);
  bf16* wfc2_b = (bf16*)alloc((size_t)DHID*MLPH*2);
  bf16* wexp_b = (bf16*)alloc((size_t)DHID*CDIM*2);
  bf16* wlin_b = (bf16*)alloc((size_t)CDIM*DHID*2);
  float* xb    = (float*)alloc(NT*CDIM*4);
  bf16* clsln  = (bf16*)alloc((size_t)NWIN*CDIM*2);
  bf16* qkvcls = (bf16*)alloc((size_t)NWIN*QKVD*2);
  bf16* ycls   = (bf16*)alloc((size_t)NWIN*CDIM*2);

  int CH_W = 2048;
  const size_t per_window = 652800ull;
  while (CH_W > 64 && off + (size_t)CH_W*per_window + 16384 > ws_size) CH_W >>= 1;
  const int CH_T = CH_W * NTOK;

  bf16*  xln  = (bf16*) alloc((size_t)CH_T*CDIM*2);
  bf16*  qkvc = (bf16*) alloc((size_t)CH_T*QKVD*2);
  bf16*  ybfc = (bf16*) alloc((size_t)CH_T*CDIM*2);   // reused as xln2 after proj
  bf16*  idc  = (bf16*) alloc((size_t)CH_T*DHID*2);
  bf16*  h1c  = (bf16*) alloc((size_t)CH_T*MLPH*2);
  bf16*  tmpc = (bf16*) alloc((size_t)CH_T*DHID*2);

  cvt6_kernel<<<512, 256, 0, stream>>>(
      w_qkv, wqkv_b, QKVD*CDIM,  w_proj, wproj_b, CDIM*CDIM,
      w_fc1, wfc1_b, MLPH*CDIM,  w_fc2,  wfc2_b,  DHID*MLPH,
      w_exp, wexp_b, DHID*CDIM,  w_lin,  wlin_b,  CDIM*DHID);

  hipMemcpyAsync(xb, x_in, NT*CDIM*4, hipMemcpyDeviceToDevice, stream);

  // ---- cls path ----
  ln_kernel<false><<<NWIN/4, 256, 0, stream>>>(x_in, (long)NTOK*CDIM, g0, b0, clsln, NWIN);
  gemm_qkv_k<<<dim3(QKVD/128, NWIN/128), 256, 0, stream>>>(
      clsln, wqkv_b, qkvcls, nullptr, nullptr, NWIN, QKVD, CDIM, QKVD, 0);
  attn_cls_kernel<<<dim3(IMGS, NHEADS), 256, 0, stream>>>(qkvcls, ycls);
  gemm_proj_k<<<dim3(CDIM/128, NWIN/128), 256, 0, stream>>>(
      ycls, wproj_b, xb, b_proj, x_in, NWIN, CDIM, CDIM, NTOK*CDIM, NTOK*CDIM);

  // ---- main chunk loop ----
  const int nch = NWIN / CH_W;
  for (int c = 0; c < nch; c++){
    int w0 = c * CH_W;
    size_t t0 = (size_t)w0 * NTOK;
    float* xbc = xb + t0*CDIM;
    int MT = CH_T, MB = CH_T/128;

    ln_kernel<false><<<MT/4, 256, 0, stream>>>(xbc, CDIM, g1, b1, xln, MT);
    gemm_qkv_k<<<dim3(QKVD/128, MB), 256, 0, stream>>>(
        xln, wqkv_b, qkvc, nullptr, nullptr, MT, QKVD, CDIM, QKVD, 0);
    attn_win_kernel<<<dim3(CH_W, NHEADS), 256, 0, stream>>>(
        qkvc, maskp + (size_t)w0*2500, rel_pos, ybfc);
    gemm_proj_k<<<dim3(CDIM/128, MB), 256, 0, stream>>>(
        ybfc, wproj_b, xbc, b_proj, xbc, MT, CDIM, CDIM, CDIM, CDIM);

    // dual LN: expand(gelu) into xln, mlp into ybfc (dead after proj)
    ln_dual_kernel<<<MT/4, 256, 0, stream>>>(xbc, ge, be, g2, b2, xln, ybfc, MT);

    gemm_exp_k<<<dim3(DHID/128, MB), 256, 0, stream>>>(
        xln, wexp_b, idc, b_exp, nullptr, MT, DHID, CDIM, DHID, 0);

    gemm_fc1_k<<<dim3(MLPH/128, MB), 256, 0, stream>>>(
        ybfc, wfc1_b, h1c, b_fc1, nullptr, MT, MLPH, CDIM, MLPH, 0);
    gemm_fc2_k<<<dim3(DHID/128, MB), 256, 0, stream>>>(
        h1c, wfc2_b, tmpc, b_fc2, idc, MT, DHID, MLPH, DHID, DHID);

    gemm_lin_k<<<dim3(CDIM/128, MB), 256, 0, stream>>>(
        tmpc, wlin_b, dout + t0*CDIM, b_lin, nullptr, MT, CDIM, DHID, CDIM, 0);
  }
}

// Round 5
// 2223.189 us; speedup vs baseline: 1.5401x; 1.1905x over previous
//
#include <hip/hip_runtime.h>
#include <hip/hip_bf16.h>
#include <math.h>

#define NHEADS 12
#define NTOK   50
#define NWIN   2048
#define IMGS   32
#define CDIM   384
#define QKVD   1152
#define DHID   768
#define MLPH   3072
#define SCALE_F 0.17677669529663687f

typedef short short8 __attribute__((ext_vector_type(8)));
typedef short short2v __attribute__((ext_vector_type(2)));
typedef float f32x4  __attribute__((ext_vector_type(4)));
typedef __hip_bfloat16 bf16;

__device__ __forceinline__ float gelu_f(float x){
  return 0.5f*x*(1.0f+erff(x*0.7071067811865476f));
}
__device__ __forceinline__ short bfs(float x){
  bf16 h = __float2bfloat16(x); return *(short*)&h;
}

// ---------------- weights fp32 -> bf16 (4 tensors) ----------------
__global__ void cvt4_kernel(const float* s0, bf16* d0, int n0,
                            const float* s1, bf16* d1, int n1,
                            const float* s2, bf16* d2, int n2,
                            const float* s3, bf16* d3, int n3){
  int stride = gridDim.x*blockDim.x, g = blockIdx.x*blockDim.x + threadIdx.x;
  for (int i=g; i<n0; i+=stride) d0[i] = __float2bfloat16(s0[i]);
  for (int i=g; i<n1; i+=stride) d1[i] = __float2bfloat16(s1[i]);
  for (int i=g; i<n2; i+=stride) d2[i] = __float2bfloat16(s2[i]);
  for (int i=g; i<n3; i+=stride) d3[i] = __float2bfloat16(s3[i]);
}

// ---------------- transpose + cvt: src[R][Cc] fp32 -> dst[Cc][R] bf16 ------------
__global__ __launch_bounds__(256) void transpose_cvt_kernel(const float* __restrict__ src,
    bf16* __restrict__ dst, int R, int Cc){
  __shared__ float tile[32][33];
  int bx = blockIdx.x, by = blockIdx.y;
  int c = threadIdx.x & 31, r0 = threadIdx.x >> 5;
  #pragma unroll
  for (int rr = r0; rr < 32; rr += 8)
    tile[rr][c] = src[(size_t)(by*32+rr)*Cc + bx*32 + c];
  __syncthreads();
  #pragma unroll
  for (int rr = r0; rr < 32; rr += 8)
    dst[(size_t)(bx*32+rr)*R + by*32 + c] = __float2bfloat16(tile[c][rr]);
}

// ---------------- bias_c = b_lin + w_lin * (b_exp + b_fc2) ----------------
__global__ void bias_combine_kernel(const float* __restrict__ wlin,
    const float* __restrict__ b_lin, const float* __restrict__ b_exp,
    const float* __restrict__ b_fc2, float* __restrict__ biasc){
  int i = blockIdx.x*blockDim.x + threadIdx.x;
  if (i >= CDIM) return;
  float s = b_lin[i];
  for (int d=0; d<DHID; d++) s += wlin[(size_t)i*DHID+d]*(b_exp[d]+b_fc2[d]);
  biasc[i] = s;
}

// ---------------- LayerNorm, fp32 in -> bf16 out ----------------
template<bool GELU>
__global__ __launch_bounds__(256) void ln_kernel(const float* __restrict__ x, long ldx,
    const float* __restrict__ g, const float* __restrict__ b,
    bf16* __restrict__ y, int rows)
{
  int row = blockIdx.x*4 + (threadIdx.x>>6);
  if (row >= rows) return;
  int l = threadIdx.x & 63;
  const float2* xr = (const float2*)(x + (size_t)row*ldx);
  float2 v[3]; float s = 0.f;
  #pragma unroll
  for (int j=0;j<3;j++){ v[j] = xr[l + 64*j]; s += v[j].x + v[j].y; }
  #pragma unroll
  for (int off=32; off; off>>=1) s += __shfl_xor(s, off, 64);
  float mean = s * (1.0f/384.0f);
  float vs = 0.f;
  #pragma unroll
  for (int j=0;j<3;j++){ float dx=v[j].x-mean, dy=v[j].y-mean; vs += dx*dx+dy*dy; }
  #pragma unroll
  for (int off=32; off; off>>=1) vs += __shfl_xor(vs, off, 64);
  float rstd = rsqrtf(vs*(1.0f/384.0f) + 1e-5f);
  short2v* yr = (short2v*)(y + (size_t)row*384);
  const float2* gv = (const float2*)g; const float2* bv = (const float2*)b;
  #pragma unroll
  for (int j=0;j<3;j++){
    float2 gg = gv[l+64*j], bb = bv[l+64*j];
    float o0 = (v[j].x-mean)*rstd*gg.x + bb.x;
    float o1 = (v[j].y-mean)*rstd*gg.y + bb.y;
    if (GELU){ o0 = gelu_f(o0); o1 = gelu_f(o1); }
    short2v pk; pk[0]=bfs(o0); pk[1]=bfs(o1);
    yr[l+64*j] = pk;
  }
}

// ---------------- dual LayerNorm: one read, two outputs ----------
__global__ __launch_bounds__(256) void ln_dual_kernel(const float* __restrict__ x,
    const float* __restrict__ ge, const float* __restrict__ be,
    const float* __restrict__ g2, const float* __restrict__ b2,
    bf16* __restrict__ yeo, bf16* __restrict__ y2o, int rows)
{
  int row = blockIdx.x*4 + (threadIdx.x>>6);
  if (row >= rows) return;
  int l = threadIdx.x & 63;
  const float2* xr = (const float2*)(x + (size_t)row*384);
  float2 v[3]; float s = 0.f;
  #pragma unroll
  for (int j=0;j<3;j++){ v[j] = xr[l + 64*j]; s += v[j].x + v[j].y; }
  #pragma unroll
  for (int off=32; off; off>>=1) s += __shfl_xor(s, off, 64);
  float mean = s * (1.0f/384.0f);
  float vs = 0.f;
  #pragma unroll
  for (int j=0;j<3;j++){ float dx=v[j].x-mean, dy=v[j].y-mean; vs += dx*dx+dy*dy; }
  #pragma unroll
  for (int off=32; off; off>>=1) vs += __shfl_xor(vs, off, 64);
  float rstd = rsqrtf(vs*(1.0f/384.0f) + 1e-5f);
  short2v* ye = (short2v*)(yeo + (size_t)row*384);
  short2v* y2 = (short2v*)(y2o + (size_t)row*384);
  const float2* gev = (const float2*)ge; const float2* bev = (const float2*)be;
  const float2* g2v = (const float2*)g2; const float2* b2v = (const float2*)b2;
  #pragma unroll
  for (int j=0;j<3;j++){
    float n0 = (v[j].x-mean)*rstd, n1 = (v[j].y-mean)*rstd;
    float2 gg = gev[l+64*j], bb = bev[l+64*j];
    short2v pe; pe[0]=bfs(gelu_f(n0*gg.x+bb.x)); pe[1]=bfs(gelu_f(n1*gg.y+bb.y));
    ye[l+64*j] = pe;
    gg = g2v[l+64*j]; bb = b2v[l+64*j];
    short2v p2; p2[0]=bfs(n0*gg.x+bb.x); p2[1]=bfs(n1*gg.y+bb.y);
    y2[l+64*j] = p2;
  }
}

// ---------------- GEMM device body: C[M,N] = A[M,K] * W[N,K]^T, bf16 in fp32 acc ------
// 128x128 tile, 4 waves, 16x16x32 MFMA, depth-2 prefetch (3 LDS buffers, counted vmcnt),
// XCD-bijective swizzle. M%128==0, N%128==0, K%64==0.
template<bool OUT_BF16, bool BIAS, int RES, bool GELU>   // RES: 0=none 1=fp32 2=bf16
__device__ __forceinline__ void gemm_dev(
    const bf16* __restrict__ A, const bf16* __restrict__ B, void* Cv,
    const float* __restrict__ bias, const void* res,
    int M, int N, int K, int ldc, int ldres)
{
  __shared__ short As[3][128*32];
  __shared__ short Bs[3][128*32];
  const int t  = threadIdx.x;
  const int l  = t & 63;
  const int w  = t >> 6;
  const int wr = w >> 1, wc = w & 1;
  const int lr = l & 15, kg = l >> 4;

  const int nwg = gridDim.x * gridDim.y;
  const int lin = blockIdx.y * gridDim.x + blockIdx.x;
  const int q8 = nwg >> 3, r8 = nwg & 7;
  const int xcd = lin & 7, slot = lin >> 3;
  const int swz = (xcd < r8) ? (xcd*(q8+1) + slot) : (r8*(q8+1) + (xcd-r8)*q8 + slot);
  const int by = swz / gridDim.x, bx = swz - by*gridDim.x;

  const int bm = by * 128, bn = bx * 128;
  const short* Ag = (const short*)A;
  const short* Bg = (const short*)B;

  const int eo0 = w*1024 + l*8;
  const int rowS0 = eo0 >> 5, colS0 = eo0 & 31;
  const int eo1 = eo0 + 512;
  const int rowS1 = eo1 >> 5, colS1 = eo1 & 31;

  #define STAGE(k0, b) do { \
    __builtin_amdgcn_global_load_lds( \
      (const __attribute__((address_space(1))) void*)&Ag[(size_t)(bm+rowS0)*K + (k0) + colS0], \
      (__attribute__((address_space(3))) void*)((char*)&As[b][0] + w*2048), 16, 0, 0); \
    __builtin_amdgcn_global_load_lds( \
      (const __attribute__((address_space(1))) void*)&Bg[(size_t)(bn+rowS0)*K + (k0) + colS0], \
      (__attribute__((address_space(3))) void*)((char*)&Bs[b][0] + w*2048), 16, 0, 0); \
    __builtin_amdgcn_global_load_lds( \
      (const __attribute__((address_space(1))) void*)&Ag[(size_t)(bm+rowS1)*K + (k0) + colS1], \
      (__attribute__((address_space(3))) void*)((char*)&As[b][0] + w*2048 + 1024), 16, 0, 0); \
    __builtin_amdgcn_global_load_lds( \
      (const __attribute__((address_space(1))) void*)&Bg[(size_t)(bn+rowS1)*K + (k0) + colS1], \
      (__attribute__((address_space(3))) void*)((char*)&Bs[b][0] + w*2048 + 1024), 16, 0, 0); \
  } while(0)

  f32x4 acc[4][4] = {};

  STAGE(0, 0);
  STAGE(32, 1);
  asm volatile("s_waitcnt vmcnt(4)" ::: "memory");
  __builtin_amdgcn_s_barrier();

  int cur = 0, nb = 2;
  for (int k0 = 0; k0 < K; k0 += 32) {
    const bool more = (k0 + 64 < K);
    if (more) STAGE(k0 + 64, nb);

    short8 af[4], bfm[4];
    #pragma unroll
    for (int m=0;m<4;m++) af[m]  = *(const short8*)(&As[cur][(wr*64 + m*16 + lr)*32 + kg*8]);
    #pragma unroll
    for (int n=0;n<4;n++) bfm[n] = *(const short8*)(&Bs[cur][(wc*64 + n*16 + lr)*32 + kg*8]);
    __builtin_amdgcn_s_setprio(1);
    #pragma unroll
    for (int m=0;m<4;m++)
      #pragma unroll
      for (int n=0;n<4;n++)
        acc[m][n] = __builtin_amdgcn_mfma_f32_16x16x32_bf16(af[m], bfm[n], acc[m][n], 0,0,0);
    __builtin_amdgcn_s_setprio(0);

    if (more) { asm volatile("s_waitcnt vmcnt(4)" ::: "memory"); }
    else      { asm volatile("s_waitcnt vmcnt(0)" ::: "memory"); }
    __builtin_amdgcn_s_barrier();
    cur = (cur==2) ? 0 : cur+1;
    nb  = (nb==2)  ? 0 : nb+1;
  }
  #undef STAGE

  #pragma unroll
  for (int m=0;m<4;m++){
    int row0 = bm + wr*64 + m*16 + kg*4;
    #pragma unroll
    for (int n=0;n<4;n++){
      int col = bn + wc*64 + n*16 + lr;
      float bv = BIAS ? bias[col] : 0.0f;
      #pragma unroll
      for (int r=0;r<4;r++){
        float val = acc[m][n][r] + bv;
        if (RES == 1) val += ((const float*)res)[(size_t)(row0+r)*ldres + col];
        if (RES == 2) val += __bfloat162float(((const bf16*)res)[(size_t)(row0+r)*ldres + col]);
        if (GELU) val = gelu_f(val);
        if (OUT_BF16) ((bf16*)Cv)[(size_t)(row0+r)*ldc + col] = __float2bfloat16(val);
        else          ((float*)Cv)[(size_t)(row0+r)*ldc + col] = val;
      }
    }
  }
}

#define GEMM_K(NAME, OB, BI, RE, GE) \
__global__ __launch_bounds__(256) void NAME( \
    const bf16* __restrict__ A, const bf16* __restrict__ B, void* Cv, \
    const float* __restrict__ bias, const void* res, \
    int M, int N, int K, int ldc, int ldres){ \
  gemm_dev<OB,BI,RE,GE>(A,B,Cv,bias,res,M,N,K,ldc,ldres); }

GEMM_K(gemm_qkv_k,  true,  false, 0, false)   // qkv: bf16 out
GEMM_K(gemm_proj_k, false, true,  1, false)   // proj: +bias, +fp32 res, fp32 out
GEMM_K(gemm_fc1_k,  true,  true,  0, true)    // fc1: +bias, gelu, bf16 out
GEMM_K(gemm_cex_k,  false, true,  0, false)   // combo-expand: +bias_c, fp32 out (dout)
GEMM_K(gemm_fch_k,  false, false, 1, false)   // combo-h: +fp32 res (dout), fp32 out
GEMM_K(gemm_wcmb_k, true,  false, 0, false)   // weight-combo precompute, bf16 out

// ---------------- cls attention ----------------
__global__ __launch_bounds__(256) void attn_cls_kernel(const bf16* __restrict__ qkv,
                                                       bf16* __restrict__ y)
{
  int img = blockIdx.x, h = blockIdx.y;
  __shared__ float q[64][33], k[64][33], v[64][33];
  __shared__ float s[64][65];
  int t = threadIdx.x;
  for (int idx=t; idx<64*32; idx+=256){
    int i = idx>>5, d = idx&31;
    const bf16* base = qkv + ((size_t)(img*64+i))*QKVD + h*32 + d;
    q[i][d] = __bfloat162float(base[0]);
    k[i][d] = __bfloat162float(base[384]);
    v[i][d] = __bfloat162float(base[768]);
  }
  __syncthreads();
  for (int idx=t; idx<64*64; idx+=256){
    int i = idx>>6, j = idx&63;
    float a = 0.f;
    #pragma unroll
    for (int d=0; d<32; d++) a += q[i][d]*k[j][d];
    s[i][j] = a * SCALE_F;
  }
  __syncthreads();
  if (t < 64){
    float m = -1e30f;
    for (int j=0;j<64;j++) m = fmaxf(m, s[t][j]);
    float sum = 0.f;
    for (int j=0;j<64;j++){ float e = __expf(s[t][j]-m); s[t][j]=e; sum+=e; }
    float inv = 1.0f/sum;
    for (int j=0;j<64;j++) s[t][j] *= inv;
  }
  __syncthreads();
  for (int idx=t; idx<64*32; idx+=256){
    int i = idx>>5, d = idx&31;
    float a = 0.f;
    for (int j=0;j<64;j++) a += s[i][j]*v[j][d];
    y[((size_t)(img*64+i))*CDIM + h*32 + d] = __float2bfloat16(a);
  }
}

// ---------------- window attention ----------------
__global__ __launch_bounds__(256) void attn_win_kernel(const bf16* __restrict__ qkv,
    const float* __restrict__ mask, const float* __restrict__ rel_pos,
    bf16* __restrict__ y)
{
  int lw = blockIdx.x, h = blockIdx.y;
  __shared__ float q[50][33], k[50][33], v[50][33];
  __shared__ float s[50][51];
  __shared__ float rp[169];
  int t = threadIdx.x;
  for (int idx=t; idx<50*32; idx+=256){
    int i = idx>>5, d = idx&31;
    const bf16* base = qkv + ((size_t)(lw*50+i))*QKVD + h*32 + d;
    q[i][d] = __bfloat162float(base[0]);
    k[i][d] = __bfloat162float(base[384]);
    v[i][d] = __bfloat162float(base[768]);
  }
  for (int idx=t; idx<169; idx+=256) rp[idx] = rel_pos[idx*NHEADS + h];
  __syncthreads();
  const float* mrow = mask + (size_t)lw*2500;
  for (int idx=t; idx<2500; idx+=256){
    int i = idx/50, j = idx - i*50;
    float a = 0.f;
    #pragma unroll
    for (int d=0; d<32; d++) a += q[i][d]*k[j][d];
    a *= SCALE_F;
    if (i > 0 && j > 0){
      int qi = i-1, kj = j-1;
      int ridx = ((qi/7)-(kj/7)+6)*13 + ((qi%7)-(kj%7)+6);
      a += rp[ridx];
    }
    a += mrow[idx];
    s[i][j] = a;
  }
  __syncthreads();
  if (t < 50){
    float m = -1e30f;
    for (int j=0;j<50;j++) m = fmaxf(m, s[t][j]);
    float sum = 0.f;
    for (int j=0;j<50;j++){ float e = __expf(s[t][j]-m); s[t][j]=e; sum+=e; }
    float inv = 1.0f/sum;
    for (int j=0;j<50;j++) s[t][j] *= inv;
  }
  __syncthreads();
  for (int idx=t; idx<50*32; idx+=256){
    int i = idx>>5, d = idx&31;
    float a = 0.f;
    for (int j=0;j<50;j++) a += s[i][j]*v[j][d];
    y[((size_t)(lw*50+i))*CDIM + h*32 + d] = __float2bfloat16(a);
  }
}

// ---------------------------------------------------------------------------
extern "C" void kernel_launch(void* const* d_in, const int* in_sizes, int n_in,
                              void* d_out, int out_size, void* d_ws, size_t ws_size,
                              hipStream_t stream)
{
  const float* x_in   = (const float*)d_in[0];
  const float* maskp  = (const float*)d_in[1];
  const float* g0 = (const float*)d_in[2];  const float* b0 = (const float*)d_in[3];
  const float* g1 = (const float*)d_in[4];  const float* b1 = (const float*)d_in[5];
  const float* g2 = (const float*)d_in[6];  const float* b2 = (const float*)d_in[7];
  const float* ge = (const float*)d_in[8];  const float* be = (const float*)d_in[9];
  const float* w_qkv = (const float*)d_in[10];
  const float* w_proj= (const float*)d_in[11];
  const float* b_proj= (const float*)d_in[12];
  const float* rel_pos=(const float*)d_in[13];
  const float* w_fc1 = (const float*)d_in[14];
  const float* b_fc1 = (const float*)d_in[15];
  const float* w_fc2 = (const float*)d_in[16];
  const float* b_fc2 = (const float*)d_in[17];
  const float* w_exp = (const float*)d_in[18];
  const float* b_exp = (const float*)d_in[19];
  const float* w_lin = (const float*)d_in[20];
  const float* b_lin = (const float*)d_in[21];
  float* dout = (float*)d_out;

  const size_t NT = (size_t)NWIN * NTOK;

  size_t off = 0;
  auto alloc = [&](size_t bytes)->void* {
    void* p = (char*)d_ws + off;
    off += (bytes + 255) & ~(size_t)255;
    return p;
  };

  bf16* wqkv_b = (bf16*)alloc((size_t)QKVD*CDIM*2);
  bf16* wproj_b= (bf16*)alloc((size_t)CDIM*CDIM*2);
  bf16* wfc1_b = (bf16*)alloc((size_t)MLPH*CDIM*2);
  bf16* wlin_b = (bf16*)alloc((size_t)CDIM*DHID*2);
  bf16* wexpT_b= (bf16*)alloc((size_t)CDIM*DHID*2);   // w_exp^T  [384,768]
  bf16* wfc2T_b= (bf16*)alloc((size_t)MLPH*DHID*2);   // w_fc2^T  [3072,768]
  bf16* W_el   = (bf16*)alloc((size_t)CDIM*CDIM*2);   // w_lin*w_exp  [384,384]
  bf16* W_h    = (bf16*)alloc((size_t)CDIM*MLPH*2);   // w_lin*w_fc2  [384,3072]
  float* biasc = (float*)alloc((size_t)CDIM*4);
  float* xb    = (float*)alloc(NT*CDIM*4);
  bf16* clsln  = (bf16*)alloc((size_t)NWIN*CDIM*2);
  bf16* qkvcls = (bf16*)alloc((size_t)NWIN*QKVD*2);
  bf16* ycls   = (bf16*)alloc((size_t)NWIN*CDIM*2);

  // per-window: xln 38400 + qkvc 115200 + ybfc 38400 + h1c 307200 = 499200
  int CH_W = 2048;
  const size_t per_window = 499200ull;
  while (CH_W > 64 && off + (size_t)CH_W*per_window + 16384 > ws_size) CH_W >>= 1;
  const int CH_T = CH_W * NTOK;

  bf16*  xln  = (bf16*) alloc((size_t)CH_T*CDIM*2);
  bf16*  qkvc = (bf16*) alloc((size_t)CH_T*QKVD*2);
  bf16*  ybfc = (bf16*) alloc((size_t)CH_T*CDIM*2);
  bf16*  h1c  = (bf16*) alloc((size_t)CH_T*MLPH*2);

  // ---- precompute: converts, transposes, combined weights/bias ----
  cvt4_kernel<<<512, 256, 0, stream>>>(
      w_qkv, wqkv_b, QKVD*CDIM,  w_proj, wproj_b, CDIM*CDIM,
      w_fc1, wfc1_b, MLPH*CDIM,  w_lin,  wlin_b,  CDIM*DHID);
  transpose_cvt_kernel<<<dim3(CDIM/32, DHID/32), 256, 0, stream>>>(w_exp, wexpT_b, DHID, CDIM);
  transpose_cvt_kernel<<<dim3(MLPH/32, DHID/32), 256, 0, stream>>>(w_fc2, wfc2T_b, DHID, MLPH);
  bias_combine_kernel<<<6, 64, 0, stream>>>(w_lin, b_lin, b_exp, b_fc2, biasc);
  // W_el[384,384] = w_lin[384,768] x (w_exp^T)[384,768]^T
  gemm_wcmb_k<<<dim3(CDIM/128, CDIM/128), 256, 0, stream>>>(
      wlin_b, wexpT_b, W_el, nullptr, nullptr, CDIM, CDIM, DHID, CDIM, 0);
  // W_h[384,3072] = w_lin[384,768] x (w_fc2^T)[3072,768]^T
  gemm_wcmb_k<<<dim3(MLPH/128, CDIM/128), 256, 0, stream>>>(
      wlin_b, wfc2T_b, W_h, nullptr, nullptr, CDIM, MLPH, DHID, MLPH, 0);

  hipMemcpyAsync(xb, x_in, NT*CDIM*4, hipMemcpyDeviceToDevice, stream);

  // ---- cls path ----
  ln_kernel<false><<<NWIN/4, 256, 0, stream>>>(x_in, (long)NTOK*CDIM, g0, b0, clsln, NWIN);
  gemm_qkv_k<<<dim3(QKVD/128, NWIN/128), 256, 0, stream>>>(
      clsln, wqkv_b, qkvcls, nullptr, nullptr, NWIN, QKVD, CDIM, QKVD, 0);
  attn_cls_kernel<<<dim3(IMGS, NHEADS), 256, 0, stream>>>(qkvcls, ycls);
  gemm_proj_k<<<dim3(CDIM/128, NWIN/128), 256, 0, stream>>>(
      ycls, wproj_b, xb, b_proj, x_in, NWIN, CDIM, CDIM, NTOK*CDIM, NTOK*CDIM);

  // ---- main chunk loop ----
  const int nch = NWIN / CH_W;
  for (int c = 0; c < nch; c++){
    int w0 = c * CH_W;
    size_t t0 = (size_t)w0 * NTOK;
    float* xbc = xb + t0*CDIM;
    float* doutc = dout + t0*CDIM;
    int MT = CH_T, MB = CH_T/128;

    ln_kernel<false><<<MT/4, 256, 0, stream>>>(xbc, CDIM, g1, b1, xln, MT);
    gemm_qkv_k<<<dim3(QKVD/128, MB), 256, 0, stream>>>(
        xln, wqkv_b, qkvc, nullptr, nullptr, MT, QKVD, CDIM, QKVD, 0);
    attn_win_kernel<<<dim3(CH_W, NHEADS), 256, 0, stream>>>(
        qkvc, maskp + (size_t)w0*2500, rel_pos, ybfc);
    gemm_proj_k<<<dim3(CDIM/128, MB), 256, 0, stream>>>(
        ybfc, wproj_b, xbc, b_proj, xbc, MT, CDIM, CDIM, CDIM, CDIM);

    // dual LN: expand-gelu into xln, mlp-LN into ybfc
    ln_dual_kernel<<<MT/4, 256, 0, stream>>>(xbc, ge, be, g2, b2, xln, ybfc, MT);

    // dout = gelu(LNe(x)) @ W_el^T + bias_c
    gemm_cex_k<<<dim3(CDIM/128, MB), 256, 0, stream>>>(
        xln, W_el, doutc, biasc, nullptr, MT, CDIM, CDIM, CDIM, 0);

    // h1 = gelu(LN2(x) @ w_fc1^T + b_fc1)
    gemm_fc1_k<<<dim3(MLPH/128, MB), 256, 0, stream>>>(
        ybfc, wfc1_b, h1c, b_fc1, nullptr, MT, MLPH, CDIM, MLPH, 0);

    // dout += h1 @ W_h^T
    gemm_fch_k<<<dim3(CDIM/128, MB), 256, 0, stream>>>(
        h1c, W_h, doutc, nullptr, doutc, MT, CDIM, MLPH, CDIM, CDIM);
  }
}